// Round 3
// baseline (333.842 us; speedup 1.0000x reference)
//
#include <hip/hip_runtime.h>

#define T 1024
constexpr int Bc = 512, Nc = 40, Hc = 128, FEc = 16, Mc = 128, OUTc = 128, NPASS = 3;
constexpr int ROWP = 136;   // bf16 LDS row pitch
constexpr int NPP  = 132;   // fp32 np/r row pitch (2-way bank alias on reads/writes: free)
constexpr int EPOOL = 512;  // LDS edge pool slots (mean ~296; fallback covers overflow)

typedef __attribute__((ext_vector_type(8))) short short8;
typedef __attribute__((ext_vector_type(4))) float floatx4;
typedef __attribute__((ext_vector_type(4))) float fvec4;
typedef _Float16 half2v __attribute__((ext_vector_type(2)));
typedef _Float16 half8v __attribute__((ext_vector_type(8)));

// ws layout (bf16 elements): fragment-major B operands only (384 KB, L2-resident)
constexpr int WS_WN = 0, WS_WM = 16384, WS_WI = 32768, WS_WH = 81920, WS_WG = 131072, WS_WO = 163840;

__device__ __forceinline__ float fast_rcp(float x) { return __builtin_amdgcn_rcpf(x); }
__device__ __forceinline__ float fast_sigmoid(float x) { return fast_rcp(1.f + __expf(-x)); }
__device__ __forceinline__ float fast_tanh(float x) {
    float t = __expf(2.f * x);
    return 1.f - 2.f * fast_rcp(t + 1.f);
}
__device__ __forceinline__ float bf2f(unsigned short u) {
    union { unsigned int i; float f; } v; v.i = ((unsigned int)u) << 16; return v.f;
}
__device__ __forceinline__ unsigned short f2bf(float f) {
    union { float f; unsigned int i; } v; v.f = f;
    unsigned int r = v.i + 0x7fff + ((v.i >> 16) & 1);   // RNE
    return (unsigned short)(r >> 16);
}
__device__ __forceinline__ half2v u2h(unsigned int u) {
    union { unsigned int i; half2v h; } v; v.i = u; return v.h;
}

__device__ __forceinline__ floatx4 mm(short8 a, short8 b, floatx4 c) {
    return __builtin_amdgcn_mfma_f32_16x16x32_bf16(a, b, c, 0, 0, 0);
}
// A-fragment: A[m=lane&15][k=quad*8+j]; rows>=40 clamped (their C rows discarded)
__device__ __forceinline__ short8 afrag(const unsigned short* buf, int mt, int kt, int lane) {
    int row = mt * 16 + (lane & 15); row = row > 39 ? 39 : row;
    return *(const short8*)(buf + row * ROWP + kt * 32 + (lane >> 4) * 8);
}
__device__ __forceinline__ short8 bfrag(const unsigned short* w, int nt, int nKT, int kt, int lane) {
    return *(const short8*)(w + ((nt * nKT + kt) * 64 + lane) * 8);
}

// ---- prep: weights -> bf16 B-fragment layout in ws ----
__global__ void prep_kernel(const float* __restrict__ Wn, const float* __restrict__ Wm,
                            const float* __restrict__ Wi, const float* __restrict__ Wh,
                            const float* __restrict__ Wg, const float* __restrict__ Wo,
                            unsigned short* __restrict__ ws) {
    int c = blockIdx.x, lane = threadIdx.x;
    int quad = lane >> 4, l16 = lane & 15;
    const float* W; int N, nKT, local; unsigned short* dst;
    if (c < 32)       { W = Wn; N = 128; nKT = 4; local = c;       dst = ws + WS_WN; }
    else if (c < 64)  { W = Wm; N = 128; nKT = 4; local = c - 32;  dst = ws + WS_WM; }
    else if (c < 160) { W = Wi; N = 384; nKT = 4; local = c - 64;  dst = ws + WS_WI; }
    else if (c < 256) { W = Wh; N = 384; nKT = 4; local = c - 160; dst = ws + WS_WH; }
    else if (c < 320) { W = Wg; N = 128; nKT = 8; local = c - 256; dst = ws + WS_WG; }
    else              { W = Wo; N = 128; nKT = 8; local = c - 320; dst = ws + WS_WO; }
    int nt = local / nKT, kt = local % nKT;
    short8 v;
#pragma unroll
    for (int j = 0; j < 8; ++j) {
        int k = kt * 32 + quad * 8 + j;
        v[j] = (short)f2bf(W[k * N + nt * 16 + l16]);
    }
    *(short8*)(dst + local * 512 + lane * 8) = v;
}

// R20: T=1024 (16 waves/block). LDS unchanged (~70 KB) -> still 2 blocks/CU, but now
// 32 waves/CU = 8/SIMD (hardware max; was 4/SIMD). Wave-task split:
//   Phase A: wave = hi*8+nt8; hi selects {np via Wn | emb via Wm} (12 MFMA/wave, was 24).
//   Attention: 8 m-groups x 5 rows (per-thread edge chain halves: ~20 vs ~40).
//   Alpha: grp = hi (24 MFMA/wave, was 48). NEW barrier before beta (z now cross-wave).
//   Beta / h-ownership (hreg) / readout: waves 0-7 only, byte-identical logic to R17.
// Anti-spill rules unchanged (R18 lesson): inline bfrag in `unroll 1` kt loops; hreg
// statically indexed; launch_bounds(1024,8) pins VGPR<=64 (compiler already lands at 64).
// Numerics untouched vs R17/R19.
__global__ __launch_bounds__(T, 8) void mpnn_kernel(
    const float* __restrict__ nodes, const float* __restrict__ edges,
    const float* __restrict__ We, const float* __restrict__ bi,
    const float* __restrict__ bh, const float* __restrict__ bg,
    const float* __restrict__ bo, const unsigned short* __restrict__ ws,
    float* __restrict__ out)
{
    __shared__ __attribute__((aligned(16))) unsigned short s_hb[Nc * ROWP];   // bf16 h
    __shared__ __attribute__((aligned(16))) unsigned short s_mb[Nc * ROWP];   // messages / nodes(cat)
    __shared__ __attribute__((aligned(16))) float s_np[Nc * NPP];             // np fp32, then r-gate fp32
    __shared__ __attribute__((aligned(16))) unsigned short s_eb[Nc * ROWP];   // emb, then z (init: slot_src)
    __shared__ __attribute__((aligned(16))) _Float16 s_poolh[EPOOL * FEc];    // 16 KB f16 edge features
    __shared__ unsigned char s_nbr[Nc][Nc];
    __shared__ int s_cnt[Nc];
    __shared__ int s_off[Nc];
    __shared__ int s_total;

    const int b = blockIdx.x, tid = threadIdx.x;
    const int lane = tid & 63, wave = tid >> 6;          // 16 waves
    const int quad = lane >> 4, l16 = lane & 15;
    const int hi = wave >> 3, nt8 = wave & 7;            // wave-task split
    const int m = tid & 127, g = tid >> 7;               // attention: g in 0..7
    const int col = nt8 * 16 + l16;

    const float* nodes_b = nodes + (size_t)b * Nc * Hc;
    const float* edges_b = edges + (size_t)b * Nc * Nc * FEc;
    const unsigned short* wWn = ws + WS_WN; const unsigned short* wWm = ws + WS_WM;
    const unsigned short* wWi = ws + WS_WI; const unsigned short* wWh = ws + WS_WH;
    const unsigned short* wWg = ws + WS_WG; const unsigned short* wWo = ws + WS_WO;

    // ---- init: h fp32 in registers on waves 0-7 (static map), bf16 in LDS ----
    float hreg[3][4];
    if (hi == 0) {
#pragma unroll
        for (int mt = 0; mt < 3; ++mt)
#pragma unroll
            for (int reg = 0; reg < 4; ++reg) {
                int row = mt * 16 + quad * 4 + reg;
                float v = (row < Nc) ? nodes_b[row * Hc + col] : 0.f;
                hreg[mt][reg] = v;
                if (row < Nc) s_hb[row * ROWP + col] = f2bf(v);
            }
    }
    // ---- adjacency scan (streaming, non-temporal) ----
    for (int p = tid; p < Nc * Nc; p += T) {
        const fvec4* e4 = (const fvec4*)(edges_b + p * FEc);
        fvec4 a0 = __builtin_nontemporal_load(e4);
        fvec4 a1 = __builtin_nontemporal_load(e4 + 1);
        fvec4 a2 = __builtin_nontemporal_load(e4 + 2);
        fvec4 a3 = __builtin_nontemporal_load(e4 + 3);
        float s = a0.x + a0.y + a0.z + a0.w + a1.x + a1.y + a1.z + a1.w
                + a2.x + a2.y + a2.z + a2.w + a3.x + a3.y + a3.z + a3.w;
        ((unsigned char*)s_nbr)[p] = (s > 0.f) ? 1 : 0;
    }
    __syncthreads();
    // ---- wave-ballot compaction: wave w owns rows i = w, w+16, ... ----
#pragma unroll 1
    for (int i = wave; i < Nc; i += 16) {
        unsigned char v = (lane < Nc) ? s_nbr[i][lane] : 0;
        unsigned long long mask = __ballot(v != 0);
        int rank = __popcll(mask & ((1ull << lane) - 1ull));
        if (v) s_nbr[i][rank] = (unsigned char)lane;   // wave-lockstep read-before-write: safe
        if (lane == 0) s_cnt[i] = __popcll(mask);
    }
    __syncthreads();
    if (wave == 0) {   // single-wave inclusive shfl-scan for offsets
        int c = (lane < Nc) ? s_cnt[lane] : 0;
        int s = c;
#pragma unroll
        for (int d = 1; d < 64; d <<= 1) {
            int t = __shfl_up(s, d);
            if (lane >= d) s += t;
        }
        if (lane < Nc) s_off[lane] = s - c;             // exclusive
        if (lane == Nc - 1) s_total = s;
    }
    __syncthreads();
    int* slot_src = (int*)s_eb;   // temp alias; dead before pass-0 Phase A writes s_eb
#pragma unroll 1
    for (int i = wave; i < Nc; i += 16) {
        int base = s_off[i], cnt = s_cnt[i];
        if (lane < cnt) {
            int slot = base + lane;
            if (slot < EPOOL) slot_src[slot] = i * Nc + s_nbr[i][lane];
        }
    }
    __syncthreads();
    {   // fill compact f16 edge pool (once; reused all 3 passes)
        const int E = s_total < EPOOL ? s_total : EPOOL;
#pragma unroll 1
        for (int w = tid; w < E * 2; w += T) {
            int s = w >> 1, hf = w & 1;
            const float* src = edges_b + (size_t)slot_src[s] * FEc + hf * 8;
            fvec4 x = __builtin_nontemporal_load((const fvec4*)src);
            fvec4 y = __builtin_nontemporal_load((const fvec4*)(src + 4));
            half8v v;
            v[0] = (_Float16)x.x; v[1] = (_Float16)x.y; v[2] = (_Float16)x.z; v[3] = (_Float16)x.w;
            v[4] = (_Float16)y.x; v[5] = (_Float16)y.y; v[6] = (_Float16)y.z; v[7] = (_Float16)y.w;
            *(half8v*)(s_poolh + s * FEc + hf * 8) = v;
        }
    }
    __syncthreads();

    for (int pass = 0; pass < NPASS; ++pass) {
        // ---- Phase A: wave task = (hi: np via Wn | emb via Wm), nt = nt8 ----
        {
            const unsigned short* wb = hi ? wWm : wWn;
            short8 bfr[4];
#pragma unroll
            for (int kt = 0; kt < 4; ++kt) bfr[kt] = bfrag(wb, nt8, 4, kt, lane);
#pragma unroll 1
            for (int mt = 0; mt < 3; ++mt) {
                floatx4 acc = {0.f, 0.f, 0.f, 0.f};
#pragma unroll
                for (int kt = 0; kt < 4; ++kt) acc = mm(afrag(s_hb, mt, kt, lane), bfr[kt], acc);
#pragma unroll
                for (int reg = 0; reg < 4; ++reg) {
                    int row = mt * 16 + quad * 4 + reg;
                    if (row < Nc) {
                        if (hi) s_eb[row * ROWP + col] = f2bf(acc[reg]);
                        else    s_np[row * NPP + col] = acc[reg];
                    }
                }
            }
        }
        __syncthreads();

        // ---- Attention: 8 groups x 5 rows; f16 pool + v_dot2_f32_f16 ----
        {
#if __has_builtin(__builtin_amdgcn_fdot2)
            half2v wh[8];
#pragma unroll
            for (int f = 0; f < 8; ++f)
                wh[f] = (half2v){(_Float16)We[(2 * f) * Mc + m], (_Float16)We[(2 * f + 1) * Mc + m]};
#else
            float wef[FEc];
#pragma unroll
            for (int f = 0; f < FEc; ++f) wef[f] = We[f * Mc + m];
#endif
#pragma unroll 1
            for (int ib = 0; ib < 5; ++ib) {
                int i = g + ib * 8;
                int cnt = s_cnt[i], base = s_off[i];
                int cap = EPOOL - base; if (cap > cnt) cap = cnt; if (cap < 0) cap = 0;
                float pden = 0.f, pnum = 0.f;
                int kn = 0;
#pragma unroll 1
                for (; kn < cap; ++kn) {
                    int j = s_nbr[i][kn];
                    const uint4* e = (const uint4*)(s_poolh + (base + kn) * FEc);
                    uint4 p0 = e[0], p1 = e[1];
#if __has_builtin(__builtin_amdgcn_fdot2)
                    float ep = 0.f;
                    ep = __builtin_amdgcn_fdot2(u2h(p0.x), wh[0], ep, false);
                    ep = __builtin_amdgcn_fdot2(u2h(p0.y), wh[1], ep, false);
                    ep = __builtin_amdgcn_fdot2(u2h(p0.z), wh[2], ep, false);
                    ep = __builtin_amdgcn_fdot2(u2h(p0.w), wh[3], ep, false);
                    ep = __builtin_amdgcn_fdot2(u2h(p1.x), wh[4], ep, false);
                    ep = __builtin_amdgcn_fdot2(u2h(p1.y), wh[5], ep, false);
                    ep = __builtin_amdgcn_fdot2(u2h(p1.z), wh[6], ep, false);
                    ep = __builtin_amdgcn_fdot2(u2h(p1.w), wh[7], ep, false);
#else
                    half2v h0 = u2h(p0.x), h1 = u2h(p0.y), h2 = u2h(p0.z), h3 = u2h(p0.w);
                    half2v h4 = u2h(p1.x), h5 = u2h(p1.y), h6 = u2h(p1.z), h7 = u2h(p1.w);
                    float ep = (float)h0.x*wef[0] + (float)h0.y*wef[1] + (float)h1.x*wef[2] + (float)h1.y*wef[3]
                             + (float)h2.x*wef[4] + (float)h2.y*wef[5] + (float)h3.x*wef[6] + (float)h3.y*wef[7]
                             + (float)h4.x*wef[8] + (float)h4.y*wef[9] + (float)h5.x*wef[10]+ (float)h5.y*wef[11]
                             + (float)h6.x*wef[12]+ (float)h6.y*wef[13]+ (float)h7.x*wef[14]+ (float)h7.y*wef[15];
#endif
                    float x = ep + s_np[j * NPP + m];
                    float w = __expf(fast_tanh(x));   // logits in (-1,1): no max-sub needed
                    pden += w;
                    pnum += w * bf2f(s_eb[j * ROWP + m]);
                }
#pragma unroll 1
                for (; kn < cnt; ++kn) {   // pool-overflow tail (statistically never)
                    int j = s_nbr[i][kn];
                    const float4* ef = (const float4*)(edges_b + ((size_t)i * Nc + j) * FEc);
                    float4 a0 = ef[0], a1 = ef[1], a2 = ef[2], a3 = ef[3];
                    float ep = a0.x*We[0*Mc+m] + a0.y*We[1*Mc+m] + a0.z*We[2*Mc+m] + a0.w*We[3*Mc+m]
                             + a1.x*We[4*Mc+m] + a1.y*We[5*Mc+m] + a1.z*We[6*Mc+m] + a1.w*We[7*Mc+m]
                             + a2.x*We[8*Mc+m] + a2.y*We[9*Mc+m] + a2.z*We[10*Mc+m]+ a2.w*We[11*Mc+m]
                             + a3.x*We[12*Mc+m]+ a3.y*We[13*Mc+m]+ a3.z*We[14*Mc+m]+ a3.w*We[15*Mc+m];
                    float w = __expf(fast_tanh(ep + s_np[j * NPP + m]));
                    pden += w;
                    pnum += w * bf2f(s_eb[j * ROWP + m]);
                }
                s_mb[i * ROWP + m] = f2bf((cnt > 0) ? pnum * fast_rcp(pden) : 0.f);
            }
        }
        __syncthreads();

        // ---- GRU alpha: wave task = grp = hi; r (fp32, s_np), z (bf16, s_eb) ----
        {
            const int grp = hi;
            float bb = bi[grp * 128 + col] + bh[grp * 128 + col];
#pragma unroll 1
            for (int mt = 0; mt < 3; ++mt) {
                floatx4 acc = {0.f,0.f,0.f,0.f};
#pragma unroll 1
                for (int kt = 0; kt < 4; ++kt) {
                    acc = mm(afrag(s_mb, mt, kt, lane), bfrag(wWi, grp * 8 + nt8, 4, kt, lane), acc);
                    acc = mm(afrag(s_hb, mt, kt, lane), bfrag(wWh, grp * 8 + nt8, 4, kt, lane), acc);
                }
#pragma unroll
                for (int reg = 0; reg < 4; ++reg) {
                    int row = mt * 16 + quad * 4 + reg;
                    if (row < Nc) {
                        float sg = fast_sigmoid(acc[reg] + bb);
                        if (grp) s_eb[row * ROWP + col] = f2bf(sg);
                        else     s_np[row * NPP + col] = sg;
                    }
                }
            }
        }
        __syncthreads();   // z produced by hi=1 waves, consumed by hi=0 in beta

        // ---- GRU beta (waves 0-7): candidate + h update into hreg ----
        if (hi == 0) {
            float bnI = bi[256 + col], bnH = bh[256 + col];
#pragma unroll
            for (int mt = 0; mt < 3; ++mt) {
                floatx4 ai = {0.f,0.f,0.f,0.f}, ah = {0.f,0.f,0.f,0.f};
#pragma unroll 1
                for (int kt = 0; kt < 4; ++kt) {
                    ai = mm(afrag(s_mb, mt, kt, lane), bfrag(wWi, 16 + nt8, 4, kt, lane), ai);
                    ah = mm(afrag(s_hb, mt, kt, lane), bfrag(wWh, 16 + nt8, 4, kt, lane), ah);
                }
#pragma unroll
                for (int reg = 0; reg < 4; ++reg) {
                    int row = mt * 16 + quad * 4 + reg;
                    if (row < Nc) {
                        float hold = hreg[mt][reg];
                        float r = s_np[row * NPP + col];
                        float z = bf2f(s_eb[row * ROWP + col]);
                        float n = fast_tanh(ai[reg] + bnI + r * (ah[reg] + bnH));
                        float v = (1.f - z) * n + z * hold;
                        hreg[mt][reg] = (s_cnt[row] > 0) ? v : hold;
                    }
                }
            }
        }
        __syncthreads();   // all afrag reads of s_hb complete before overwrite
        if (hi == 0) {
#pragma unroll
            for (int mt = 0; mt < 3; ++mt)
#pragma unroll
                for (int reg = 0; reg < 4; ++reg) {
                    int row = mt * 16 + quad * 4 + reg;
                    if (row < Nc) s_hb[row * ROWP + col] = f2bf(hreg[mt][reg]);
                }
        }
        __syncthreads();
    }

    // ---- Readout: out = sum_i mask * sigmoid(cat@Wg+bg) * (cat@Wo+bo) ----
    for (int idx = tid; idx < Nc * Hc; idx += T) {
        int row = idx >> 7, c2 = idx & 127;
        s_mb[row * ROWP + c2] = f2bf(nodes_b[idx]);   // cat tail (messages dead)
    }
    __syncthreads();
    if (hi == 0) {
        float psum = 0.f;
        {
            float bgv = bg[col], bov = bo[col];
#pragma unroll 1
            for (int mt = 0; mt < 3; ++mt) {
                floatx4 ga = {0.f,0.f,0.f,0.f}, oa = {0.f,0.f,0.f,0.f};
#pragma unroll 1
                for (int kt = 0; kt < 8; ++kt) {
                    short8 a = (kt < 4) ? afrag(s_hb, mt, kt, lane) : afrag(s_mb, mt, kt - 4, lane);
                    ga = mm(a, bfrag(wWg, nt8, 8, kt, lane), ga);
                    oa = mm(a, bfrag(wWo, nt8, 8, kt, lane), oa);
                }
#pragma unroll
                for (int reg = 0; reg < 4; ++reg) {
                    int row = mt * 16 + quad * 4 + reg;
                    if (row < Nc && s_cnt[row] > 0)
                        psum += fast_sigmoid(ga[reg] + bgv) * (oa[reg] + bov);
                }
            }
        }
        psum += __shfl_xor(psum, 16);   // reduce the 4 quads sharing this col
        psum += __shfl_xor(psum, 32);
        if (quad == 0) out[(size_t)b * OUTc + col] = psum;
    }
}

extern "C" void kernel_launch(void* const* d_in, const int* in_sizes, int n_in,
                              void* d_out, int out_size, void* d_ws, size_t ws_size,
                              hipStream_t stream) {
    const float* nodes = (const float*)d_in[0];
    const float* edges = (const float*)d_in[1];
    const float* We = (const float*)d_in[2];
    const float* Wn = (const float*)d_in[3];
    const float* Wm = (const float*)d_in[4];
    const float* Wi = (const float*)d_in[5];
    const float* Wh = (const float*)d_in[6];
    const float* bi = (const float*)d_in[7];
    const float* bh = (const float*)d_in[8];
    const float* Wg = (const float*)d_in[9];
    const float* bg = (const float*)d_in[10];
    const float* Wo = (const float*)d_in[11];
    const float* bo = (const float*)d_in[12];
    float* out = (float*)d_out;
    unsigned short* ws = (unsigned short*)d_ws;

    prep_kernel<<<384, 64, 0, stream>>>(Wn, Wm, Wi, Wh, Wg, Wo, ws);
    mpnn_kernel<<<Bc, T, 0, stream>>>(nodes, edges, We, bi, bh, bg, bo, ws, out);
}

// Round 4
// 293.708 us; speedup vs baseline: 1.1366x; 1.1366x over previous
//
#include <hip/hip_runtime.h>

#define T 1024
constexpr int Bc = 512, Nc = 40, Hc = 128, FEc = 16, Mc = 128, OUTc = 128, NPASS = 3;
constexpr int ROWP = 136;   // bf16 LDS row pitch
constexpr int NPP  = 132;   // fp32 np/r row pitch (2-way bank alias on reads/writes: free)
constexpr int EPOOL = 512;  // LDS edge pool slots (mean ~296; fallback covers overflow)

typedef __attribute__((ext_vector_type(8))) short short8;
typedef __attribute__((ext_vector_type(4))) float floatx4;
typedef __attribute__((ext_vector_type(4))) float fvec4;
typedef _Float16 half2v __attribute__((ext_vector_type(2)));
typedef _Float16 half8v __attribute__((ext_vector_type(8)));

// ws layout (bf16 elements): fragment-major B operands only (384 KB, L2-resident)
constexpr int WS_WN = 0, WS_WM = 16384, WS_WI = 32768, WS_WH = 81920, WS_WG = 131072, WS_WO = 163840;

__device__ __forceinline__ float fast_rcp(float x) { return __builtin_amdgcn_rcpf(x); }
__device__ __forceinline__ float fast_sigmoid(float x) { return fast_rcp(1.f + __expf(-x)); }
__device__ __forceinline__ float fast_tanh(float x) {
    float t = __expf(2.f * x);
    return 1.f - 2.f * fast_rcp(t + 1.f);
}
__device__ __forceinline__ float bf2f(unsigned short u) {
    union { unsigned int i; float f; } v; v.i = ((unsigned int)u) << 16; return v.f;
}
__device__ __forceinline__ unsigned short f2bf(float f) {
    union { float f; unsigned int i; } v; v.f = f;
    unsigned int r = v.i + 0x7fff + ((v.i >> 16) & 1);   // RNE
    return (unsigned short)(r >> 16);
}
__device__ __forceinline__ half2v u2h(unsigned int u) {
    union { unsigned int i; half2v h; } v; v.i = u; return v.h;
}

__device__ __forceinline__ floatx4 mm(short8 a, short8 b, floatx4 c) {
    return __builtin_amdgcn_mfma_f32_16x16x32_bf16(a, b, c, 0, 0, 0);
}
// A-fragment: A[m=lane&15][k=quad*8+j]; rows>=40 clamped (their C rows discarded)
__device__ __forceinline__ short8 afrag(const unsigned short* buf, int mt, int kt, int lane) {
    int row = mt * 16 + (lane & 15); row = row > 39 ? 39 : row;
    return *(const short8*)(buf + row * ROWP + kt * 32 + (lane >> 4) * 8);
}
__device__ __forceinline__ short8 bfrag(const unsigned short* w, int nt, int nKT, int kt, int lane) {
    return *(const short8*)(w + ((nt * nKT + kt) * 64 + lane) * 8);
}

// ---- prep: weights -> bf16 B-fragment layout in ws ----
__global__ void prep_kernel(const float* __restrict__ Wn, const float* __restrict__ Wm,
                            const float* __restrict__ Wi, const float* __restrict__ Wh,
                            const float* __restrict__ Wg, const float* __restrict__ Wo,
                            unsigned short* __restrict__ ws) {
    int c = blockIdx.x, lane = threadIdx.x;
    int quad = lane >> 4, l16 = lane & 15;
    const float* W; int N, nKT, local; unsigned short* dst;
    if (c < 32)       { W = Wn; N = 128; nKT = 4; local = c;       dst = ws + WS_WN; }
    else if (c < 64)  { W = Wm; N = 128; nKT = 4; local = c - 32;  dst = ws + WS_WM; }
    else if (c < 160) { W = Wi; N = 384; nKT = 4; local = c - 64;  dst = ws + WS_WI; }
    else if (c < 256) { W = Wh; N = 384; nKT = 4; local = c - 160; dst = ws + WS_WH; }
    else if (c < 320) { W = Wg; N = 128; nKT = 8; local = c - 256; dst = ws + WS_WG; }
    else              { W = Wo; N = 128; nKT = 8; local = c - 320; dst = ws + WS_WO; }
    int nt = local / nKT, kt = local % nKT;
    short8 v;
#pragma unroll
    for (int j = 0; j < 8; ++j) {
        int k = kt * 32 + quad * 8 + j;
        v[j] = (short)f2bf(W[k * N + nt * 16 + l16]);
    }
    *(short8*)(dst + local * 512 + lane * 8) = v;
}

// R20 structure (T=1024, 16 waves, wave-task split) reached 85% occupancy but spilled:
// launch_bounds 2nd arg behaves as MIN WORKGROUPS/CU in this toolchain (evidence:
// (512,4)->VGPR 64 ok; (1024,8)->VGPR 32 + 500MB scratch traffic; 8 blocks x 16 waves
// is 32 waves/EU -> 16-VGPR cap). R21: __launch_bounds__(1024, 2) -> 2 blocks x 16
// waves = 8 waves/EU -> 64-VGPR cap = the footprint this per-thread code already
// compiles to. Everything else byte-identical to R20:
//   Phase A: wave = hi*8+nt8; hi selects {np via Wn | emb via Wm} (12 MFMA/wave).
//   Attention: 8 m-groups x 5 rows (per-thread edge chain ~20 vs R17's ~40).
//   Alpha: grp = hi (24 MFMA/wave). Barrier before beta (z produced cross-wave).
//   Beta / h-ownership (hreg) / readout: waves 0-7 only, logic identical to R17.
// Tripwire: if VGPR_Count != 64 or WRITE_SIZE >> 20 MB, revert to R19.
__global__ __launch_bounds__(T, 2) void mpnn_kernel(
    const float* __restrict__ nodes, const float* __restrict__ edges,
    const float* __restrict__ We, const float* __restrict__ bi,
    const float* __restrict__ bh, const float* __restrict__ bg,
    const float* __restrict__ bo, const unsigned short* __restrict__ ws,
    float* __restrict__ out)
{
    __shared__ __attribute__((aligned(16))) unsigned short s_hb[Nc * ROWP];   // bf16 h
    __shared__ __attribute__((aligned(16))) unsigned short s_mb[Nc * ROWP];   // messages / nodes(cat)
    __shared__ __attribute__((aligned(16))) float s_np[Nc * NPP];             // np fp32, then r-gate fp32
    __shared__ __attribute__((aligned(16))) unsigned short s_eb[Nc * ROWP];   // emb, then z (init: slot_src)
    __shared__ __attribute__((aligned(16))) _Float16 s_poolh[EPOOL * FEc];    // 16 KB f16 edge features
    __shared__ unsigned char s_nbr[Nc][Nc];
    __shared__ int s_cnt[Nc];
    __shared__ int s_off[Nc];
    __shared__ int s_total;

    const int b = blockIdx.x, tid = threadIdx.x;
    const int lane = tid & 63, wave = tid >> 6;          // 16 waves
    const int quad = lane >> 4, l16 = lane & 15;
    const int hi = wave >> 3, nt8 = wave & 7;            // wave-task split
    const int m = tid & 127, g = tid >> 7;               // attention: g in 0..7
    const int col = nt8 * 16 + l16;

    const float* nodes_b = nodes + (size_t)b * Nc * Hc;
    const float* edges_b = edges + (size_t)b * Nc * Nc * FEc;
    const unsigned short* wWn = ws + WS_WN; const unsigned short* wWm = ws + WS_WM;
    const unsigned short* wWi = ws + WS_WI; const unsigned short* wWh = ws + WS_WH;
    const unsigned short* wWg = ws + WS_WG; const unsigned short* wWo = ws + WS_WO;

    // ---- init: h fp32 in registers on waves 0-7 (static map), bf16 in LDS ----
    float hreg[3][4];
    if (hi == 0) {
#pragma unroll
        for (int mt = 0; mt < 3; ++mt)
#pragma unroll
            for (int reg = 0; reg < 4; ++reg) {
                int row = mt * 16 + quad * 4 + reg;
                float v = (row < Nc) ? nodes_b[row * Hc + col] : 0.f;
                hreg[mt][reg] = v;
                if (row < Nc) s_hb[row * ROWP + col] = f2bf(v);
            }
    }
    // ---- adjacency scan (streaming, non-temporal) ----
    for (int p = tid; p < Nc * Nc; p += T) {
        const fvec4* e4 = (const fvec4*)(edges_b + p * FEc);
        fvec4 a0 = __builtin_nontemporal_load(e4);
        fvec4 a1 = __builtin_nontemporal_load(e4 + 1);
        fvec4 a2 = __builtin_nontemporal_load(e4 + 2);
        fvec4 a3 = __builtin_nontemporal_load(e4 + 3);
        float s = a0.x + a0.y + a0.z + a0.w + a1.x + a1.y + a1.z + a1.w
                + a2.x + a2.y + a2.z + a2.w + a3.x + a3.y + a3.z + a3.w;
        ((unsigned char*)s_nbr)[p] = (s > 0.f) ? 1 : 0;
    }
    __syncthreads();
    // ---- wave-ballot compaction: wave w owns rows i = w, w+16, ... ----
#pragma unroll 1
    for (int i = wave; i < Nc; i += 16) {
        unsigned char v = (lane < Nc) ? s_nbr[i][lane] : 0;
        unsigned long long mask = __ballot(v != 0);
        int rank = __popcll(mask & ((1ull << lane) - 1ull));
        if (v) s_nbr[i][rank] = (unsigned char)lane;   // wave-lockstep read-before-write: safe
        if (lane == 0) s_cnt[i] = __popcll(mask);
    }
    __syncthreads();
    if (wave == 0) {   // single-wave inclusive shfl-scan for offsets
        int c = (lane < Nc) ? s_cnt[lane] : 0;
        int s = c;
#pragma unroll
        for (int d = 1; d < 64; d <<= 1) {
            int t = __shfl_up(s, d);
            if (lane >= d) s += t;
        }
        if (lane < Nc) s_off[lane] = s - c;             // exclusive
        if (lane == Nc - 1) s_total = s;
    }
    __syncthreads();
    int* slot_src = (int*)s_eb;   // temp alias; dead before pass-0 Phase A writes s_eb
#pragma unroll 1
    for (int i = wave; i < Nc; i += 16) {
        int base = s_off[i], cnt = s_cnt[i];
        if (lane < cnt) {
            int slot = base + lane;
            if (slot < EPOOL) slot_src[slot] = i * Nc + s_nbr[i][lane];
        }
    }
    __syncthreads();
    {   // fill compact f16 edge pool (once; reused all 3 passes)
        const int E = s_total < EPOOL ? s_total : EPOOL;
#pragma unroll 1
        for (int w = tid; w < E * 2; w += T) {
            int s = w >> 1, hf = w & 1;
            const float* src = edges_b + (size_t)slot_src[s] * FEc + hf * 8;
            fvec4 x = __builtin_nontemporal_load((const fvec4*)src);
            fvec4 y = __builtin_nontemporal_load((const fvec4*)(src + 4));
            half8v v;
            v[0] = (_Float16)x.x; v[1] = (_Float16)x.y; v[2] = (_Float16)x.z; v[3] = (_Float16)x.w;
            v[4] = (_Float16)y.x; v[5] = (_Float16)y.y; v[6] = (_Float16)y.z; v[7] = (_Float16)y.w;
            *(half8v*)(s_poolh + s * FEc + hf * 8) = v;
        }
    }
    __syncthreads();

    for (int pass = 0; pass < NPASS; ++pass) {
        // ---- Phase A: wave task = (hi: np via Wn | emb via Wm), nt = nt8 ----
        {
            const unsigned short* wb = hi ? wWm : wWn;
            short8 bfr[4];
#pragma unroll
            for (int kt = 0; kt < 4; ++kt) bfr[kt] = bfrag(wb, nt8, 4, kt, lane);
#pragma unroll 1
            for (int mt = 0; mt < 3; ++mt) {
                floatx4 acc = {0.f, 0.f, 0.f, 0.f};
#pragma unroll
                for (int kt = 0; kt < 4; ++kt) acc = mm(afrag(s_hb, mt, kt, lane), bfr[kt], acc);
#pragma unroll
                for (int reg = 0; reg < 4; ++reg) {
                    int row = mt * 16 + quad * 4 + reg;
                    if (row < Nc) {
                        if (hi) s_eb[row * ROWP + col] = f2bf(acc[reg]);
                        else    s_np[row * NPP + col] = acc[reg];
                    }
                }
            }
        }
        __syncthreads();

        // ---- Attention: 8 groups x 5 rows; f16 pool + v_dot2_f32_f16 ----
        {
#if __has_builtin(__builtin_amdgcn_fdot2)
            half2v wh[8];
#pragma unroll
            for (int f = 0; f < 8; ++f)
                wh[f] = (half2v){(_Float16)We[(2 * f) * Mc + m], (_Float16)We[(2 * f + 1) * Mc + m]};
#else
            float wef[FEc];
#pragma unroll
            for (int f = 0; f < FEc; ++f) wef[f] = We[f * Mc + m];
#endif
#pragma unroll 1
            for (int ib = 0; ib < 5; ++ib) {
                int i = g + ib * 8;
                int cnt = s_cnt[i], base = s_off[i];
                int cap = EPOOL - base; if (cap > cnt) cap = cnt; if (cap < 0) cap = 0;
                float pden = 0.f, pnum = 0.f;
                int kn = 0;
#pragma unroll 1
                for (; kn < cap; ++kn) {
                    int j = s_nbr[i][kn];
                    const uint4* e = (const uint4*)(s_poolh + (base + kn) * FEc);
                    uint4 p0 = e[0], p1 = e[1];
#if __has_builtin(__builtin_amdgcn_fdot2)
                    float ep = 0.f;
                    ep = __builtin_amdgcn_fdot2(u2h(p0.x), wh[0], ep, false);
                    ep = __builtin_amdgcn_fdot2(u2h(p0.y), wh[1], ep, false);
                    ep = __builtin_amdgcn_fdot2(u2h(p0.z), wh[2], ep, false);
                    ep = __builtin_amdgcn_fdot2(u2h(p0.w), wh[3], ep, false);
                    ep = __builtin_amdgcn_fdot2(u2h(p1.x), wh[4], ep, false);
                    ep = __builtin_amdgcn_fdot2(u2h(p1.y), wh[5], ep, false);
                    ep = __builtin_amdgcn_fdot2(u2h(p1.z), wh[6], ep, false);
                    ep = __builtin_amdgcn_fdot2(u2h(p1.w), wh[7], ep, false);
#else
                    half2v h0 = u2h(p0.x), h1 = u2h(p0.y), h2 = u2h(p0.z), h3 = u2h(p0.w);
                    half2v h4 = u2h(p1.x), h5 = u2h(p1.y), h6 = u2h(p1.z), h7 = u2h(p1.w);
                    float ep = (float)h0.x*wef[0] + (float)h0.y*wef[1] + (float)h1.x*wef[2] + (float)h1.y*wef[3]
                             + (float)h2.x*wef[4] + (float)h2.y*wef[5] + (float)h3.x*wef[6] + (float)h3.y*wef[7]
                             + (float)h4.x*wef[8] + (float)h4.y*wef[9] + (float)h5.x*wef[10]+ (float)h5.y*wef[11]
                             + (float)h6.x*wef[12]+ (float)h6.y*wef[13]+ (float)h7.x*wef[14]+ (float)h7.y*wef[15];
#endif
                    float x = ep + s_np[j * NPP + m];
                    float w = __expf(fast_tanh(x));   // logits in (-1,1): no max-sub needed
                    pden += w;
                    pnum += w * bf2f(s_eb[j * ROWP + m]);
                }
#pragma unroll 1
                for (; kn < cnt; ++kn) {   // pool-overflow tail (statistically never)
                    int j = s_nbr[i][kn];
                    const float4* ef = (const float4*)(edges_b + ((size_t)i * Nc + j) * FEc);
                    float4 a0 = ef[0], a1 = ef[1], a2 = ef[2], a3 = ef[3];
                    float ep = a0.x*We[0*Mc+m] + a0.y*We[1*Mc+m] + a0.z*We[2*Mc+m] + a0.w*We[3*Mc+m]
                             + a1.x*We[4*Mc+m] + a1.y*We[5*Mc+m] + a1.z*We[6*Mc+m] + a1.w*We[7*Mc+m]
                             + a2.x*We[8*Mc+m] + a2.y*We[9*Mc+m] + a2.z*We[10*Mc+m]+ a2.w*We[11*Mc+m]
                             + a3.x*We[12*Mc+m]+ a3.y*We[13*Mc+m]+ a3.z*We[14*Mc+m]+ a3.w*We[15*Mc+m];
                    float w = __expf(fast_tanh(ep + s_np[j * NPP + m]));
                    pden += w;
                    pnum += w * bf2f(s_eb[j * ROWP + m]);
                }
                s_mb[i * ROWP + m] = f2bf((cnt > 0) ? pnum * fast_rcp(pden) : 0.f);
            }
        }
        __syncthreads();

        // ---- GRU alpha: wave task = grp = hi; r (fp32, s_np), z (bf16, s_eb) ----
        {
            const int grp = hi;
            float bb = bi[grp * 128 + col] + bh[grp * 128 + col];
#pragma unroll 1
            for (int mt = 0; mt < 3; ++mt) {
                floatx4 acc = {0.f,0.f,0.f,0.f};
#pragma unroll 1
                for (int kt = 0; kt < 4; ++kt) {
                    acc = mm(afrag(s_mb, mt, kt, lane), bfrag(wWi, grp * 8 + nt8, 4, kt, lane), acc);
                    acc = mm(afrag(s_hb, mt, kt, lane), bfrag(wWh, grp * 8 + nt8, 4, kt, lane), acc);
                }
#pragma unroll
                for (int reg = 0; reg < 4; ++reg) {
                    int row = mt * 16 + quad * 4 + reg;
                    if (row < Nc) {
                        float sg = fast_sigmoid(acc[reg] + bb);
                        if (grp) s_eb[row * ROWP + col] = f2bf(sg);
                        else     s_np[row * NPP + col] = sg;
                    }
                }
            }
        }
        __syncthreads();   // z produced by hi=1 waves, consumed by hi=0 in beta

        // ---- GRU beta (waves 0-7): candidate + h update into hreg ----
        if (hi == 0) {
            float bnI = bi[256 + col], bnH = bh[256 + col];
#pragma unroll
            for (int mt = 0; mt < 3; ++mt) {
                floatx4 ai = {0.f,0.f,0.f,0.f}, ah = {0.f,0.f,0.f,0.f};
#pragma unroll 1
                for (int kt = 0; kt < 4; ++kt) {
                    ai = mm(afrag(s_mb, mt, kt, lane), bfrag(wWi, 16 + nt8, 4, kt, lane), ai);
                    ah = mm(afrag(s_hb, mt, kt, lane), bfrag(wWh, 16 + nt8, 4, kt, lane), ah);
                }
#pragma unroll
                for (int reg = 0; reg < 4; ++reg) {
                    int row = mt * 16 + quad * 4 + reg;
                    if (row < Nc) {
                        float hold = hreg[mt][reg];
                        float r = s_np[row * NPP + col];
                        float z = bf2f(s_eb[row * ROWP + col]);
                        float n = fast_tanh(ai[reg] + bnI + r * (ah[reg] + bnH));
                        float v = (1.f - z) * n + z * hold;
                        hreg[mt][reg] = (s_cnt[row] > 0) ? v : hold;
                    }
                }
            }
        }
        __syncthreads();   // all afrag reads of s_hb complete before overwrite
        if (hi == 0) {
#pragma unroll
            for (int mt = 0; mt < 3; ++mt)
#pragma unroll
                for (int reg = 0; reg < 4; ++reg) {
                    int row = mt * 16 + quad * 4 + reg;
                    if (row < Nc) s_hb[row * ROWP + col] = f2bf(hreg[mt][reg]);
                }
        }
        __syncthreads();
    }

    // ---- Readout: out = sum_i mask * sigmoid(cat@Wg+bg) * (cat@Wo+bo) ----
    for (int idx = tid; idx < Nc * Hc; idx += T) {
        int row = idx >> 7, c2 = idx & 127;
        s_mb[row * ROWP + c2] = f2bf(nodes_b[idx]);   // cat tail (messages dead)
    }
    __syncthreads();
    if (hi == 0) {
        float psum = 0.f;
        {
            float bgv = bg[col], bov = bo[col];
#pragma unroll 1
            for (int mt = 0; mt < 3; ++mt) {
                floatx4 ga = {0.f,0.f,0.f,0.f}, oa = {0.f,0.f,0.f,0.f};
#pragma unroll 1
                for (int kt = 0; kt < 8; ++kt) {
                    short8 a = (kt < 4) ? afrag(s_hb, mt, kt, lane) : afrag(s_mb, mt, kt - 4, lane);
                    ga = mm(a, bfrag(wWg, nt8, 8, kt, lane), ga);
                    oa = mm(a, bfrag(wWo, nt8, 8, kt, lane), oa);
                }
#pragma unroll
                for (int reg = 0; reg < 4; ++reg) {
                    int row = mt * 16 + quad * 4 + reg;
                    if (row < Nc && s_cnt[row] > 0)
                        psum += fast_sigmoid(ga[reg] + bgv) * (oa[reg] + bov);
                }
            }
        }
        psum += __shfl_xor(psum, 16);   // reduce the 4 quads sharing this col
        psum += __shfl_xor(psum, 32);
        if (quad == 0) out[(size_t)b * OUTc + col] = psum;
    }
}

extern "C" void kernel_launch(void* const* d_in, const int* in_sizes, int n_in,
                              void* d_out, int out_size, void* d_ws, size_t ws_size,
                              hipStream_t stream) {
    const float* nodes = (const float*)d_in[0];
    const float* edges = (const float*)d_in[1];
    const float* We = (const float*)d_in[2];
    const float* Wn = (const float*)d_in[3];
    const float* Wm = (const float*)d_in[4];
    const float* Wi = (const float*)d_in[5];
    const float* Wh = (const float*)d_in[6];
    const float* bi = (const float*)d_in[7];
    const float* bh = (const float*)d_in[8];
    const float* Wg = (const float*)d_in[9];
    const float* bg = (const float*)d_in[10];
    const float* Wo = (const float*)d_in[11];
    const float* bo = (const float*)d_in[12];
    float* out = (float*)d_out;
    unsigned short* ws = (unsigned short*)d_ws;

    prep_kernel<<<384, 64, 0, stream>>>(Wn, Wm, Wi, Wh, Wg, Wo, ws);
    mpnn_kernel<<<Bc, T, 0, stream>>>(nodes, edges, We, bi, bh, bg, bo, ws, out);
}

// Round 6
// 287.845 us; speedup vs baseline: 1.1598x; 1.0204x over previous
//
#include <hip/hip_runtime.h>

#define T 512
constexpr int Bc = 512, Nc = 40, Hc = 128, FEc = 16, Mc = 128, OUTc = 128, NPASS = 3;
constexpr int ROWP = 136;   // bf16 LDS row pitch
constexpr int NPP  = 132;   // fp32 np/r row pitch (2-way bank alias on reads/writes: free)
constexpr int EPOOL = 512;  // LDS edge pool slots (mean ~296; fallback covers overflow)

typedef __attribute__((ext_vector_type(8))) short short8;
typedef __attribute__((ext_vector_type(4))) float floatx4;
typedef __attribute__((ext_vector_type(4))) float fvec4;
typedef _Float16 half2v __attribute__((ext_vector_type(2)));
typedef _Float16 half8v __attribute__((ext_vector_type(8)));

// ws layout (bf16/u16 elements): fragment-major B operands (384 KB, L2-resident),
// then optional per-block f16 ep cache: ws[WS_EPC + b*EPOOL*128 + slot*128 + m].
constexpr int WS_WN = 0, WS_WM = 16384, WS_WI = 32768, WS_WH = 81920, WS_WG = 131072, WS_WO = 163840;
constexpr size_t WS_EPC = 196608;                      // elem offset of ep cache
constexpr size_t EPC_PER_BLOCK = (size_t)EPOOL * 128;  // elems per block
constexpr size_t WS_NEED_BYTES = 2 * (WS_EPC + (size_t)Bc * EPC_PER_BLOCK);  // 67,502,080

__device__ __forceinline__ float fast_rcp(float x) { return __builtin_amdgcn_rcpf(x); }
__device__ __forceinline__ float fast_sigmoid(float x) { return fast_rcp(1.f + __expf(-x)); }
__device__ __forceinline__ float fast_tanh(float x) {
    float t = __expf(2.f * x);
    return 1.f - 2.f * fast_rcp(t + 1.f);
}
__device__ __forceinline__ float bf2f(unsigned short u) {
    union { unsigned int i; float f; } v; v.i = ((unsigned int)u) << 16; return v.f;
}
__device__ __forceinline__ unsigned short f2bf(float f) {
    union { float f; unsigned int i; } v; v.f = f;
    unsigned int r = v.i + 0x7fff + ((v.i >> 16) & 1);   // RNE
    return (unsigned short)(r >> 16);
}
__device__ __forceinline__ half2v u2h(unsigned int u) {
    union { unsigned int i; half2v h; } v; v.i = u; return v.h;
}
__device__ __forceinline__ unsigned short f2h_bits(float f) {
    _Float16 h = (_Float16)f;
    union { _Float16 h; unsigned short u; } v; v.h = h; return v.u;
}
__device__ __forceinline__ float h_bits2f(unsigned short u) {
    union { unsigned short u; _Float16 h; } v; v.u = u; return (float)v.h;
}

__device__ __forceinline__ floatx4 mm(short8 a, short8 b, floatx4 c) {
    return __builtin_amdgcn_mfma_f32_16x16x32_bf16(a, b, c, 0, 0, 0);
}
// A-fragment: A[m=lane&15][k=quad*8+j]; rows>=40 clamped (their C rows discarded)
__device__ __forceinline__ short8 afrag(const unsigned short* buf, int mt, int kt, int lane) {
    int row = mt * 16 + (lane & 15); row = row > 39 ? 39 : row;
    return *(const short8*)(buf + row * ROWP + kt * 32 + (lane >> 4) * 8);
}
__device__ __forceinline__ short8 bfrag(const unsigned short* w, int nt, int nKT, int kt, int lane) {
    return *(const short8*)(w + ((nt * nKT + kt) * 64 + lane) * 8);
}

// ---- prep: weights -> bf16 B-fragment layout in ws ----
__global__ void prep_kernel(const float* __restrict__ Wn, const float* __restrict__ Wm,
                            const float* __restrict__ Wi, const float* __restrict__ Wh,
                            const float* __restrict__ Wg, const float* __restrict__ Wo,
                            unsigned short* __restrict__ ws) {
    int c = blockIdx.x, lane = threadIdx.x;
    int quad = lane >> 4, l16 = lane & 15;
    const float* W; int N, nKT, local; unsigned short* dst;
    if (c < 32)       { W = Wn; N = 128; nKT = 4; local = c;       dst = ws + WS_WN; }
    else if (c < 64)  { W = Wm; N = 128; nKT = 4; local = c - 32;  dst = ws + WS_WM; }
    else if (c < 160) { W = Wi; N = 384; nKT = 4; local = c - 64;  dst = ws + WS_WI; }
    else if (c < 256) { W = Wh; N = 384; nKT = 4; local = c - 160; dst = ws + WS_WH; }
    else if (c < 320) { W = Wg; N = 128; nKT = 8; local = c - 256; dst = ws + WS_WG; }
    else              { W = Wo; N = 128; nKT = 8; local = c - 320; dst = ws + WS_WO; }
    int nt = local / nKT, kt = local % nKT;
    short8 v;
#pragma unroll
    for (int j = 0; j < 8; ++j) {
        int k = kt * 32 + quad * 8 + j;
        v[j] = (short)f2bf(W[k * N + nt * 16 + l16]);
    }
    *(short8*)(dst + local * 512 + lane * 8) = v;
}

// T=512, 8 waves, LDS ~70 KB -> 2 blocks/CU (4 waves/SIMD). Occupancy is GRID-capped
// (512 blocks / 256 CUs = 2/CU): more blocks/CU is impossible; T=1024 spilled (R20/R21).
// R9/R10/R12-proven anti-spill rules: (1) attention reads LDS pool only; (2) GEMM mt/kt
// loops `unroll 1`; (3) private arrays only in fully-unrolled code; (4) no per-thread
// state persists across barriers.
// R18 FAILED: GRU B-frag hoist -> scratch spills. R20/R21 FAILED: T=1024 wave-split ->
// hreg spills around barriers (WRITE 68-267MB; launch_bounds 2nd arg = min WORKGROUPS/CU
// in this toolchain: (512,4)->64 VGPR, (1024,8)->32, (1024,2)->64).
// R22 (resubmitted R23 after infra-only container failure): ep = edge.We[:,m] is
// PASS-INVARIANT. Pass 0 computes it (fdot2, as R19) and stores f16 to a per-block
// global ws cache; passes 1-2 load it (1-deep prefetch) instead of 8 fdot2 + 2 LDS
// b128 per edge (~10 of ~30 issue slots, 2 of 3 passes).
// Host guard: ecap = (ws_size >= 67.5MB) ? EPOOL : 0; ecap=0 degenerates to exact R19.
// Cache rewritten by pass 0 every launch (re-poison safe). Per-row branch wave-uniform.
__global__ __launch_bounds__(T, 4) void mpnn_kernel(
    const float* __restrict__ nodes, const float* __restrict__ edges,
    const float* __restrict__ We, const float* __restrict__ bi,
    const float* __restrict__ bh, const float* __restrict__ bg,
    const float* __restrict__ bo, unsigned short* __restrict__ ws,
    float* __restrict__ out, int ecap)
{
    __shared__ __attribute__((aligned(16))) unsigned short s_hb[Nc * ROWP];   // bf16 h
    __shared__ __attribute__((aligned(16))) unsigned short s_mb[Nc * ROWP];   // messages / nodes(cat)
    __shared__ __attribute__((aligned(16))) float s_np[Nc * NPP];             // np fp32, then r-gate fp32
    __shared__ __attribute__((aligned(16))) unsigned short s_eb[Nc * ROWP];   // emb, then z (init: slot_src)
    __shared__ __attribute__((aligned(16))) _Float16 s_poolh[EPOOL * FEc];    // 16 KB f16 edge features
    __shared__ unsigned char s_nbr[Nc][Nc];
    __shared__ int s_cnt[Nc];
    __shared__ int s_off[Nc];
    __shared__ int s_total;

    const int b = blockIdx.x, tid = threadIdx.x;
    const int lane = tid & 63, wave = tid >> 6;          // 8 waves; nt = wave
    const int quad = lane >> 4, l16 = lane & 15;
    const int m = tid & 127, g = tid >> 7;               // attention: g in 0..3 (wave-uniform)
    const int col = wave * 16 + l16;

    const float* nodes_b = nodes + (size_t)b * Nc * Hc;
    const float* edges_b = edges + (size_t)b * Nc * Nc * FEc;
    const unsigned short* wWn = ws + WS_WN; const unsigned short* wWm = ws + WS_WM;
    const unsigned short* wWi = ws + WS_WI; const unsigned short* wWh = ws + WS_WH;
    const unsigned short* wWg = ws + WS_WG; const unsigned short* wWo = ws + WS_WO;
    unsigned short* epg = ws + WS_EPC + (size_t)b * EPC_PER_BLOCK;   // per-block f16 ep cache

    // ---- init: h fp32 in registers (static map, fully unrolled), bf16 in LDS ----
    float hreg[3][4];
#pragma unroll
    for (int mt = 0; mt < 3; ++mt)
#pragma unroll
        for (int reg = 0; reg < 4; ++reg) {
            int row = mt * 16 + quad * 4 + reg;
            float v = (row < Nc) ? nodes_b[row * Hc + col] : 0.f;
            hreg[mt][reg] = v;
            if (row < Nc) s_hb[row * ROWP + col] = f2bf(v);
        }
    // ---- adjacency scan (streaming, non-temporal) ----
    for (int p = tid; p < Nc * Nc; p += T) {
        const fvec4* e4 = (const fvec4*)(edges_b + p * FEc);
        fvec4 a0 = __builtin_nontemporal_load(e4);
        fvec4 a1 = __builtin_nontemporal_load(e4 + 1);
        fvec4 a2 = __builtin_nontemporal_load(e4 + 2);
        fvec4 a3 = __builtin_nontemporal_load(e4 + 3);
        float s = a0.x + a0.y + a0.z + a0.w + a1.x + a1.y + a1.z + a1.w
                + a2.x + a2.y + a2.z + a2.w + a3.x + a3.y + a3.z + a3.w;
        ((unsigned char*)s_nbr)[p] = (s > 0.f) ? 1 : 0;
    }
    __syncthreads();
    // ---- wave-ballot compaction: wave w owns rows i = w, w+8, ... (order-preserving) ----
#pragma unroll 1
    for (int i = wave; i < Nc; i += 8) {
        unsigned char v = (lane < Nc) ? s_nbr[i][lane] : 0;
        unsigned long long mask = __ballot(v != 0);
        int rank = __popcll(mask & ((1ull << lane) - 1ull));
        if (v) s_nbr[i][rank] = (unsigned char)lane;   // wave-lockstep read-before-write: safe
        if (lane == 0) s_cnt[i] = __popcll(mask);
    }
    __syncthreads();
    if (wave == 0) {   // single-wave inclusive shfl-scan for offsets
        int c = (lane < Nc) ? s_cnt[lane] : 0;
        int s = c;
#pragma unroll
        for (int d = 1; d < 64; d <<= 1) {
            int t = __shfl_up(s, d);
            if (lane >= d) s += t;
        }
        if (lane < Nc) s_off[lane] = s - c;             // exclusive
        if (lane == Nc - 1) s_total = s;
    }
    __syncthreads();
    int* slot_src = (int*)s_eb;   // temp alias; dead before pass-0 Phase A writes s_eb
#pragma unroll 1
    for (int i = wave; i < Nc; i += 8) {
        int base = s_off[i], cnt = s_cnt[i];
        if (lane < cnt) {
            int slot = base + lane;
            if (slot < EPOOL) slot_src[slot] = i * Nc + s_nbr[i][lane];
        }
    }
    __syncthreads();
    {   // fill compact f16 edge pool (once; reused all 3 passes)
        const int E = s_total < EPOOL ? s_total : EPOOL;
#pragma unroll 1
        for (int w = tid; w < E * 2; w += T) {
            int s = w >> 1, hf = w & 1;
            const float* src = edges_b + (size_t)slot_src[s] * FEc + hf * 8;
            fvec4 x = __builtin_nontemporal_load((const fvec4*)src);
            fvec4 y = __builtin_nontemporal_load((const fvec4*)(src + 4));
            half8v v;
            v[0] = (_Float16)x.x; v[1] = (_Float16)x.y; v[2] = (_Float16)x.z; v[3] = (_Float16)x.w;
            v[4] = (_Float16)y.x; v[5] = (_Float16)y.y; v[6] = (_Float16)y.z; v[7] = (_Float16)y.w;
            *(half8v*)(s_poolh + s * FEc + hf * 8) = v;
        }
    }
    __syncthreads();

    for (int pass = 0; pass < NPASS; ++pass) {
        // ---- Phase A: np = h@Wn (fp32 out), emb = h@Wm (bf16 out) ----
#pragma unroll 1
        for (int jb = 0; jb < 2; ++jb) {
            const unsigned short* wb = jb ? wWm : wWn;
            short8 bfr[4];
#pragma unroll
            for (int kt = 0; kt < 4; ++kt) bfr[kt] = bfrag(wb, wave, 4, kt, lane);
#pragma unroll 1
            for (int mt = 0; mt < 3; ++mt) {
                floatx4 acc = {0.f, 0.f, 0.f, 0.f};
#pragma unroll
                for (int kt = 0; kt < 4; ++kt) acc = mm(afrag(s_hb, mt, kt, lane), bfr[kt], acc);
#pragma unroll
                for (int reg = 0; reg < 4; ++reg) {
                    int row = mt * 16 + quad * 4 + reg;
                    if (row < Nc) {
                        if (jb) s_eb[row * ROWP + col] = f2bf(acc[reg]);
                        else    s_np[row * NPP + col] = acc[reg];
                    }
                }
            }
        }
        __syncthreads();

        // ---- Attention: f16 pool + v_dot2_f32_f16; ep cached in ws across passes ----
        {
#if __has_builtin(__builtin_amdgcn_fdot2)
            half2v wh[8];
#pragma unroll
            for (int f = 0; f < 8; ++f)
                wh[f] = (half2v){(_Float16)We[(2 * f) * Mc + m], (_Float16)We[(2 * f + 1) * Mc + m]};
#else
            float wef[FEc];
#pragma unroll
            for (int f = 0; f < FEc; ++f) wef[f] = We[f * Mc + m];
#endif
#pragma unroll 1
            for (int ib = 0; ib < 10; ++ib) {
                int i = g + ib * 4;
                int cnt = s_cnt[i], base = s_off[i];
                int cap = EPOOL - base; if (cap > cnt) cap = cnt; if (cap < 0) cap = 0;
                const bool cached = (cnt > 0) && (base + cnt <= ecap);   // wave-uniform
                float pden = 0.f, pnum = 0.f;
                int kn = 0;
                if (cached && pass > 0) {
                    // ---- passes 1-2: load f16 ep from cache (1-deep prefetch) ----
                    const unsigned short* ep_row = epg + (size_t)base * 128 + m;
                    unsigned short eu = ep_row[0];
#pragma unroll 1
                    for (kn = 0; kn < cnt; ++kn) {
                        float ep = h_bits2f(eu);
                        if (kn + 1 < cnt) eu = ep_row[(size_t)(kn + 1) * 128];
                        int j = s_nbr[i][kn];
                        float x = ep + s_np[j * NPP + m];
                        float w = __expf(fast_tanh(x));
                        pden += w;
                        pnum += w * bf2f(s_eb[j * ROWP + m]);
                    }
                } else {
#pragma unroll 1
                    for (; kn < cap; ++kn) {
                        int j = s_nbr[i][kn];
                        const uint4* e = (const uint4*)(s_poolh + (base + kn) * FEc);
                        uint4 p0 = e[0], p1 = e[1];
#if __has_builtin(__builtin_amdgcn_fdot2)
                        float ep = 0.f;
                        ep = __builtin_amdgcn_fdot2(u2h(p0.x), wh[0], ep, false);
                        ep = __builtin_amdgcn_fdot2(u2h(p0.y), wh[1], ep, false);
                        ep = __builtin_amdgcn_fdot2(u2h(p0.z), wh[2], ep, false);
                        ep = __builtin_amdgcn_fdot2(u2h(p0.w), wh[3], ep, false);
                        ep = __builtin_amdgcn_fdot2(u2h(p1.x), wh[4], ep, false);
                        ep = __builtin_amdgcn_fdot2(u2h(p1.y), wh[5], ep, false);
                        ep = __builtin_amdgcn_fdot2(u2h(p1.z), wh[6], ep, false);
                        ep = __builtin_amdgcn_fdot2(u2h(p1.w), wh[7], ep, false);
#else
                        half2v h0 = u2h(p0.x), h1 = u2h(p0.y), h2 = u2h(p0.z), h3 = u2h(p0.w);
                        half2v h4 = u2h(p1.x), h5 = u2h(p1.y), h6 = u2h(p1.z), h7 = u2h(p1.w);
                        float ep = (float)h0.x*wef[0] + (float)h0.y*wef[1] + (float)h1.x*wef[2] + (float)h1.y*wef[3]
                                 + (float)h2.x*wef[4] + (float)h2.y*wef[5] + (float)h3.x*wef[6] + (float)h3.y*wef[7]
                                 + (float)h4.x*wef[8] + (float)h4.y*wef[9] + (float)h5.x*wef[10]+ (float)h5.y*wef[11]
                                 + (float)h6.x*wef[12]+ (float)h6.y*wef[13]+ (float)h7.x*wef[14]+ (float)h7.y*wef[15];
#endif
                        if (cached)   // implies pass==0 in this branch; coalesced 256B/row
                            epg[(size_t)(base + kn) * 128 + m] = f2h_bits(ep);
                        float x = ep + s_np[j * NPP + m];
                        float w = __expf(fast_tanh(x));   // logits in (-1,1): no max-sub needed
                        pden += w;
                        pnum += w * bf2f(s_eb[j * ROWP + m]);
                    }
#pragma unroll 1
                    for (; kn < cnt; ++kn) {   // pool-overflow tail (statistically never)
                        int j = s_nbr[i][kn];
                        const float4* ef = (const float4*)(edges_b + ((size_t)i * Nc + j) * FEc);
                        float4 a0 = ef[0], a1 = ef[1], a2 = ef[2], a3 = ef[3];
                        float ep = a0.x*We[0*Mc+m] + a0.y*We[1*Mc+m] + a0.z*We[2*Mc+m] + a0.w*We[3*Mc+m]
                                 + a1.x*We[4*Mc+m] + a1.y*We[5*Mc+m] + a1.z*We[6*Mc+m] + a1.w*We[7*Mc+m]
                                 + a2.x*We[8*Mc+m] + a2.y*We[9*Mc+m] + a2.z*We[10*Mc+m]+ a2.w*We[11*Mc+m]
                                 + a3.x*We[12*Mc+m]+ a3.y*We[13*Mc+m]+ a3.z*We[14*Mc+m]+ a3.w*We[15*Mc+m];
                        float w = __expf(fast_tanh(ep + s_np[j * NPP + m]));
                        pden += w;
                        pnum += w * bf2f(s_eb[j * ROWP + m]);
                    }
                }
                s_mb[i * ROWP + m] = f2bf((cnt > 0) ? pnum * fast_rcp(pden) : 0.f);
            }
        }
        __syncthreads();

        // ---- GRU alpha: r (fp32 in s_np), z (bf16 in s_eb); 1 acc set live ----
#pragma unroll 1
        for (int grp = 0; grp < 2; ++grp) {
            float bb = bi[grp * 128 + col] + bh[grp * 128 + col];
#pragma unroll 1
            for (int mt = 0; mt < 3; ++mt) {
                floatx4 acc = {0.f,0.f,0.f,0.f};
#pragma unroll 1
                for (int kt = 0; kt < 4; ++kt) {
                    acc = mm(afrag(s_mb, mt, kt, lane), bfrag(wWi, grp * 8 + wave, 4, kt, lane), acc);
                    acc = mm(afrag(s_hb, mt, kt, lane), bfrag(wWh, grp * 8 + wave, 4, kt, lane), acc);
                }
#pragma unroll
                for (int reg = 0; reg < 4; ++reg) {
                    int row = mt * 16 + quad * 4 + reg;
                    if (row < Nc) {
                        float sg = fast_sigmoid(acc[reg] + bb);
                        if (grp) s_eb[row * ROWP + col] = f2bf(sg);
                        else     s_np[row * NPP + col] = sg;
                    }
                }
            }
        }
        // ---- GRU beta: candidate + h update into hreg (regs private -> pre-barrier ok) ----
        {
            float bnI = bi[256 + col], bnH = bh[256 + col];
#pragma unroll
            for (int mt = 0; mt < 3; ++mt) {
                floatx4 ai = {0.f,0.f,0.f,0.f}, ah = {0.f,0.f,0.f,0.f};
#pragma unroll 1
                for (int kt = 0; kt < 4; ++kt) {
                    ai = mm(afrag(s_mb, mt, kt, lane), bfrag(wWi, 16 + wave, 4, kt, lane), ai);
                    ah = mm(afrag(s_hb, mt, kt, lane), bfrag(wWh, 16 + wave, 4, kt, lane), ah);
                }
#pragma unroll
                for (int reg = 0; reg < 4; ++reg) {
                    int row = mt * 16 + quad * 4 + reg;
                    if (row < Nc) {
                        float hold = hreg[mt][reg];
                        float r = s_np[row * NPP + col];
                        float z = bf2f(s_eb[row * ROWP + col]);
                        float n = fast_tanh(ai[reg] + bnI + r * (ah[reg] + bnH));
                        float v = (1.f - z) * n + z * hold;
                        hreg[mt][reg] = (s_cnt[row] > 0) ? v : hold;
                    }
                }
            }
        }
        __syncthreads();   // all afrag reads of s_hb complete before overwrite
#pragma unroll
        for (int mt = 0; mt < 3; ++mt)
#pragma unroll
            for (int reg = 0; reg < 4; ++reg) {
                int row = mt * 16 + quad * 4 + reg;
                if (row < Nc) s_hb[row * ROWP + col] = f2bf(hreg[mt][reg]);
            }
        __syncthreads();
    }

    // ---- Readout: out = sum_i mask * sigmoid(cat@Wg+bg) * (cat@Wo+bo) ----
    for (int idx = tid; idx < Nc * Hc; idx += T) {
        int row = idx >> 7, c2 = idx & 127;
        s_mb[row * ROWP + c2] = f2bf(nodes_b[idx]);   // cat tail (messages dead)
    }
    __syncthreads();
    float psum = 0.f;
    {
        float bgv = bg[col], bov = bo[col];
#pragma unroll 1
        for (int mt = 0; mt < 3; ++mt) {
            floatx4 ga = {0.f,0.f,0.f,0.f}, oa = {0.f,0.f,0.f,0.f};
#pragma unroll 1
            for (int kt = 0; kt < 8; ++kt) {
                short8 a = (kt < 4) ? afrag(s_hb, mt, kt, lane) : afrag(s_mb, mt, kt - 4, lane);
                ga = mm(a, bfrag(wWg, wave, 8, kt, lane), ga);
                oa = mm(a, bfrag(wWo, wave, 8, kt, lane), oa);
            }
#pragma unroll
            for (int reg = 0; reg < 4; ++reg) {
                int row = mt * 16 + quad * 4 + reg;
                if (row < Nc && s_cnt[row] > 0)
                    psum += fast_sigmoid(ga[reg] + bgv) * (oa[reg] + bov);
            }
        }
    }
    psum += __shfl_xor(psum, 16);   // reduce the 4 quads sharing this col
    psum += __shfl_xor(psum, 32);
    if (quad == 0) out[(size_t)b * OUTc + col] = psum;
}

extern "C" void kernel_launch(void* const* d_in, const int* in_sizes, int n_in,
                              void* d_out, int out_size, void* d_ws, size_t ws_size,
                              hipStream_t stream) {
    const float* nodes = (const float*)d_in[0];
    const float* edges = (const float*)d_in[1];
    const float* We = (const float*)d_in[2];
    const float* Wn = (const float*)d_in[3];
    const float* Wm = (const float*)d_in[4];
    const float* Wi = (const float*)d_in[5];
    const float* Wh = (const float*)d_in[6];
    const float* bi = (const float*)d_in[7];
    const float* bh = (const float*)d_in[8];
    const float* Wg = (const float*)d_in[9];
    const float* bg = (const float*)d_in[10];
    const float* Wo = (const float*)d_in[11];
    const float* bo = (const float*)d_in[12];
    float* out = (float*)d_out;
    unsigned short* ws = (unsigned short*)d_ws;

    const int ecap = (ws_size >= WS_NEED_BYTES) ? EPOOL : 0;   // graceful fallback to R19 path

    prep_kernel<<<384, 64, 0, stream>>>(Wn, Wm, Wi, Wh, Wg, Wo, ws);
    mpnn_kernel<<<Bc, T, 0, stream>>>(nodes, edges, We, bi, bh, bg, bo, ws, out, ecap);
}

// Round 7
// 274.820 us; speedup vs baseline: 1.2148x; 1.0474x over previous
//
#include <hip/hip_runtime.h>

#define T 512
constexpr int Bc = 512, Nc = 40, Hc = 128, FEc = 16, Mc = 128, OUTc = 128, NPASS = 3;
constexpr int ROWP = 136;   // bf16 LDS row pitch
constexpr int NPP  = 132;   // fp32 np/r row pitch (2-way bank alias on reads/writes: free)
constexpr int EPOOL = 512;  // LDS edge pool slots (mean ~296; fallback covers overflow)

typedef __attribute__((ext_vector_type(8))) short short8;
typedef __attribute__((ext_vector_type(4))) float floatx4;
typedef __attribute__((ext_vector_type(4))) float fvec4;
typedef _Float16 half2v __attribute__((ext_vector_type(2)));
typedef _Float16 half8v __attribute__((ext_vector_type(8)));

// ws layout (bf16 elements): fragment-major B operands only (384 KB, L2-resident)
constexpr int WS_WN = 0, WS_WM = 16384, WS_WI = 32768, WS_WH = 81920, WS_WG = 131072, WS_WO = 163840;

__device__ __forceinline__ float fast_rcp(float x) { return __builtin_amdgcn_rcpf(x); }
__device__ __forceinline__ float fast_sigmoid(float x) { return fast_rcp(1.f + __expf(-x)); }
__device__ __forceinline__ float fast_tanh(float x) {
    float t = __expf(2.f * x);
    return 1.f - 2.f * fast_rcp(t + 1.f);
}
__device__ __forceinline__ float bf2f(unsigned short u) {
    union { unsigned int i; float f; } v; v.i = ((unsigned int)u) << 16; return v.f;
}
__device__ __forceinline__ unsigned short f2bf(float f) {
    union { float f; unsigned int i; } v; v.f = f;
    unsigned int r = v.i + 0x7fff + ((v.i >> 16) & 1);   // RNE
    return (unsigned short)(r >> 16);
}
__device__ __forceinline__ half2v u2h(unsigned int u) {
    union { unsigned int i; half2v h; } v; v.i = u; return v.h;
}

__device__ __forceinline__ floatx4 mm(short8 a, short8 b, floatx4 c) {
    return __builtin_amdgcn_mfma_f32_16x16x32_bf16(a, b, c, 0, 0, 0);
}
// A-fragment: A[m=lane&15][k=quad*8+j]; rows>=40 clamped (their C rows discarded)
__device__ __forceinline__ short8 afrag(const unsigned short* buf, int mt, int kt, int lane) {
    int row = mt * 16 + (lane & 15); row = row > 39 ? 39 : row;
    return *(const short8*)(buf + row * ROWP + kt * 32 + (lane >> 4) * 8);
}
__device__ __forceinline__ short8 bfrag(const unsigned short* w, int nt, int nKT, int kt, int lane) {
    return *(const short8*)(w + ((nt * nKT + kt) * 64 + lane) * 8);
}

// ---- prep: weights -> bf16 B-fragment layout in ws ----
__global__ void prep_kernel(const float* __restrict__ Wn, const float* __restrict__ Wm,
                            const float* __restrict__ Wi, const float* __restrict__ Wh,
                            const float* __restrict__ Wg, const float* __restrict__ Wo,
                            unsigned short* __restrict__ ws) {
    int c = blockIdx.x, lane = threadIdx.x;
    int quad = lane >> 4, l16 = lane & 15;
    const float* W; int N, nKT, local; unsigned short* dst;
    if (c < 32)       { W = Wn; N = 128; nKT = 4; local = c;       dst = ws + WS_WN; }
    else if (c < 64)  { W = Wm; N = 128; nKT = 4; local = c - 32;  dst = ws + WS_WM; }
    else if (c < 160) { W = Wi; N = 384; nKT = 4; local = c - 64;  dst = ws + WS_WI; }
    else if (c < 256) { W = Wh; N = 384; nKT = 4; local = c - 160; dst = ws + WS_WH; }
    else if (c < 320) { W = Wg; N = 128; nKT = 8; local = c - 256; dst = ws + WS_WG; }
    else              { W = Wo; N = 128; nKT = 8; local = c - 320; dst = ws + WS_WO; }
    int nt = local / nKT, kt = local % nKT;
    short8 v;
#pragma unroll
    for (int j = 0; j < 8; ++j) {
        int k = kt * 32 + quad * 8 + j;
        v[j] = (short)f2bf(W[k * N + nt * 16 + l16]);
    }
    *(short8*)(dst + local * 512 + lane * 8) = v;
}

// T=512, 8 waves, LDS ~70 KB -> 2 blocks/CU (4 waves/SIMD). Occupancy GRID-capped
// (512 blocks / 256 CUs = 2/CU); T=1024 spilled (R20/R21).
// launch_bounds 2nd arg = min WORKGROUPS/CU in this toolchain ((512,4)->64 VGPR cap,
// (1024,8)->32, (1024,2)->64). R24 uses (512,2): VGPR cap 128 at ZERO occupancy cost
// (LDS + grid already cap residency at 2 blocks/CU) -> removes the spill cliff.
// FAILED levers (do not retry): R18 GRU B-frag hoist (spill); R20/R21 T=1024 wave-split
// (spill around barriers); R22/R23 global f16 ep cache (latency-bound: swapped ~25cy
// fdot2 for ~200-900cy dependent load; VALUBusy 48->36 but dur 158->191. Attention is
// LATENCY-bound, not VALU-bound).
// R24: break the per-edge LDS pointer-chase (j byte-load ~120cy -> np/emb ~120cy,
// serial under unroll 1). s_nbr rows are 4-aligned: one uint load = 4 j's; the 4
// np/emb load pairs are then independent and issue together; pool/fdot2 reads are
// j-independent (affine in kn). 4-edge unrolled body (rule-3 compliant); per-edge
// amortized latency ~4x lower. Tails: <4 remainder + pool-overflow use R19 body.
__global__ __launch_bounds__(T, 2) void mpnn_kernel(
    const float* __restrict__ nodes, const float* __restrict__ edges,
    const float* __restrict__ We, const float* __restrict__ bi,
    const float* __restrict__ bh, const float* __restrict__ bg,
    const float* __restrict__ bo, const unsigned short* __restrict__ ws,
    float* __restrict__ out)
{
    __shared__ __attribute__((aligned(16))) unsigned short s_hb[Nc * ROWP];   // bf16 h
    __shared__ __attribute__((aligned(16))) unsigned short s_mb[Nc * ROWP];   // messages / nodes(cat)
    __shared__ __attribute__((aligned(16))) float s_np[Nc * NPP];             // np fp32, then r-gate fp32
    __shared__ __attribute__((aligned(16))) unsigned short s_eb[Nc * ROWP];   // emb, then z (init: slot_src)
    __shared__ __attribute__((aligned(16))) _Float16 s_poolh[EPOOL * FEc];    // 16 KB f16 edge features
    __shared__ unsigned char s_nbr[Nc][Nc];
    __shared__ int s_cnt[Nc];
    __shared__ int s_off[Nc];
    __shared__ int s_total;

    const int b = blockIdx.x, tid = threadIdx.x;
    const int lane = tid & 63, wave = tid >> 6;          // 8 waves; nt = wave
    const int quad = lane >> 4, l16 = lane & 15;
    const int m = tid & 127, g = tid >> 7;               // attention: g in 0..3 (wave-uniform)
    const int col = wave * 16 + l16;

    const float* nodes_b = nodes + (size_t)b * Nc * Hc;
    const float* edges_b = edges + (size_t)b * Nc * Nc * FEc;
    const unsigned short* wWn = ws + WS_WN; const unsigned short* wWm = ws + WS_WM;
    const unsigned short* wWi = ws + WS_WI; const unsigned short* wWh = ws + WS_WH;
    const unsigned short* wWg = ws + WS_WG; const unsigned short* wWo = ws + WS_WO;

    // ---- init: h fp32 in registers (static map, fully unrolled), bf16 in LDS ----
    float hreg[3][4];
#pragma unroll
    for (int mt = 0; mt < 3; ++mt)
#pragma unroll
        for (int reg = 0; reg < 4; ++reg) {
            int row = mt * 16 + quad * 4 + reg;
            float v = (row < Nc) ? nodes_b[row * Hc + col] : 0.f;
            hreg[mt][reg] = v;
            if (row < Nc) s_hb[row * ROWP + col] = f2bf(v);
        }
    // ---- adjacency scan (streaming, non-temporal) ----
    for (int p = tid; p < Nc * Nc; p += T) {
        const fvec4* e4 = (const fvec4*)(edges_b + p * FEc);
        fvec4 a0 = __builtin_nontemporal_load(e4);
        fvec4 a1 = __builtin_nontemporal_load(e4 + 1);
        fvec4 a2 = __builtin_nontemporal_load(e4 + 2);
        fvec4 a3 = __builtin_nontemporal_load(e4 + 3);
        float s = a0.x + a0.y + a0.z + a0.w + a1.x + a1.y + a1.z + a1.w
                + a2.x + a2.y + a2.z + a2.w + a3.x + a3.y + a3.z + a3.w;
        ((unsigned char*)s_nbr)[p] = (s > 0.f) ? 1 : 0;
    }
    __syncthreads();
    // ---- wave-ballot compaction: wave w owns rows i = w, w+8, ... (order-preserving) ----
#pragma unroll 1
    for (int i = wave; i < Nc; i += 8) {
        unsigned char v = (lane < Nc) ? s_nbr[i][lane] : 0;
        unsigned long long mask = __ballot(v != 0);
        int rank = __popcll(mask & ((1ull << lane) - 1ull));
        if (v) s_nbr[i][rank] = (unsigned char)lane;   // wave-lockstep read-before-write: safe
        if (lane == 0) s_cnt[i] = __popcll(mask);
    }
    __syncthreads();
    if (wave == 0) {   // single-wave inclusive shfl-scan for offsets
        int c = (lane < Nc) ? s_cnt[lane] : 0;
        int s = c;
#pragma unroll
        for (int d = 1; d < 64; d <<= 1) {
            int t = __shfl_up(s, d);
            if (lane >= d) s += t;
        }
        if (lane < Nc) s_off[lane] = s - c;             // exclusive
        if (lane == Nc - 1) s_total = s;
    }
    __syncthreads();
    int* slot_src = (int*)s_eb;   // temp alias; dead before pass-0 Phase A writes s_eb
#pragma unroll 1
    for (int i = wave; i < Nc; i += 8) {
        int base = s_off[i], cnt = s_cnt[i];
        if (lane < cnt) {
            int slot = base + lane;
            if (slot < EPOOL) slot_src[slot] = i * Nc + s_nbr[i][lane];
        }
    }
    __syncthreads();
    {   // fill compact f16 edge pool (once; reused all 3 passes)
        const int E = s_total < EPOOL ? s_total : EPOOL;
#pragma unroll 1
        for (int w = tid; w < E * 2; w += T) {
            int s = w >> 1, hf = w & 1;
            const float* src = edges_b + (size_t)slot_src[s] * FEc + hf * 8;
            fvec4 x = __builtin_nontemporal_load((const fvec4*)src);
            fvec4 y = __builtin_nontemporal_load((const fvec4*)(src + 4));
            half8v v;
            v[0] = (_Float16)x.x; v[1] = (_Float16)x.y; v[2] = (_Float16)x.z; v[3] = (_Float16)x.w;
            v[4] = (_Float16)y.x; v[5] = (_Float16)y.y; v[6] = (_Float16)y.z; v[7] = (_Float16)y.w;
            *(half8v*)(s_poolh + s * FEc + hf * 8) = v;
        }
    }
    __syncthreads();

    for (int pass = 0; pass < NPASS; ++pass) {
        // ---- Phase A: np = h@Wn (fp32 out), emb = h@Wm (bf16 out) ----
#pragma unroll 1
        for (int jb = 0; jb < 2; ++jb) {
            const unsigned short* wb = jb ? wWm : wWn;
            short8 bfr[4];
#pragma unroll
            for (int kt = 0; kt < 4; ++kt) bfr[kt] = bfrag(wb, wave, 4, kt, lane);
#pragma unroll 1
            for (int mt = 0; mt < 3; ++mt) {
                floatx4 acc = {0.f, 0.f, 0.f, 0.f};
#pragma unroll
                for (int kt = 0; kt < 4; ++kt) acc = mm(afrag(s_hb, mt, kt, lane), bfr[kt], acc);
#pragma unroll
                for (int reg = 0; reg < 4; ++reg) {
                    int row = mt * 16 + quad * 4 + reg;
                    if (row < Nc) {
                        if (jb) s_eb[row * ROWP + col] = f2bf(acc[reg]);
                        else    s_np[row * NPP + col] = acc[reg];
                    }
                }
            }
        }
        __syncthreads();

        // ---- Attention: f16 pool + fdot2; 4-edge batched loads (latency fix) ----
        {
#if __has_builtin(__builtin_amdgcn_fdot2)
            half2v wh[8];
#pragma unroll
            for (int f = 0; f < 8; ++f)
                wh[f] = (half2v){(_Float16)We[(2 * f) * Mc + m], (_Float16)We[(2 * f + 1) * Mc + m]};
#define EP_DOT(P0, P1, DST)                                          \
    do {                                                             \
        float _e = 0.f;                                              \
        _e = __builtin_amdgcn_fdot2(u2h((P0).x), wh[0], _e, false);  \
        _e = __builtin_amdgcn_fdot2(u2h((P0).y), wh[1], _e, false);  \
        _e = __builtin_amdgcn_fdot2(u2h((P0).z), wh[2], _e, false);  \
        _e = __builtin_amdgcn_fdot2(u2h((P0).w), wh[3], _e, false);  \
        _e = __builtin_amdgcn_fdot2(u2h((P1).x), wh[4], _e, false);  \
        _e = __builtin_amdgcn_fdot2(u2h((P1).y), wh[5], _e, false);  \
        _e = __builtin_amdgcn_fdot2(u2h((P1).z), wh[6], _e, false);  \
        _e = __builtin_amdgcn_fdot2(u2h((P1).w), wh[7], _e, false);  \
        DST = _e;                                                    \
    } while (0)
#else
            float wef[FEc];
#pragma unroll
            for (int f = 0; f < FEc; ++f) wef[f] = We[f * Mc + m];
#define EP_DOT(P0, P1, DST)                                                                        \
    do {                                                                                           \
        half2v _h0 = u2h((P0).x), _h1 = u2h((P0).y), _h2 = u2h((P0).z), _h3 = u2h((P0).w);         \
        half2v _h4 = u2h((P1).x), _h5 = u2h((P1).y), _h6 = u2h((P1).z), _h7 = u2h((P1).w);         \
        DST = (float)_h0.x*wef[0] + (float)_h0.y*wef[1] + (float)_h1.x*wef[2] + (float)_h1.y*wef[3]\
            + (float)_h2.x*wef[4] + (float)_h2.y*wef[5] + (float)_h3.x*wef[6] + (float)_h3.y*wef[7]\
            + (float)_h4.x*wef[8] + (float)_h4.y*wef[9] + (float)_h5.x*wef[10]+ (float)_h5.y*wef[11]\
            + (float)_h6.x*wef[12]+ (float)_h6.y*wef[13]+ (float)_h7.x*wef[14]+ (float)_h7.y*wef[15];\
    } while (0)
#endif
#pragma unroll 1
            for (int ib = 0; ib < 10; ++ib) {
                int i = g + ib * 4;
                int cnt = s_cnt[i], base = s_off[i];
                int cap = EPOOL - base; if (cap > cnt) cap = cnt; if (cap < 0) cap = 0;
                float pden = 0.f, pnum = 0.f;
                int kn = 0;
                // ---- 4-edge blocks: 1 uint j-load, 4 independent np/emb load pairs ----
#pragma unroll 1
                for (; kn + 4 <= cap; kn += 4) {
                    unsigned jw = *(const unsigned*)(&s_nbr[i][kn]);   // row 4-aligned (Nc=40)
                    int j0 = jw & 255, j1 = (jw >> 8) & 255, j2 = (jw >> 16) & 255, j3 = jw >> 24;
                    float n0 = s_np[j0 * NPP + m], n1 = s_np[j1 * NPP + m];
                    float n2 = s_np[j2 * NPP + m], n3 = s_np[j3 * NPP + m];
                    float e0 = bf2f(s_eb[j0 * ROWP + m]), e1 = bf2f(s_eb[j1 * ROWP + m]);
                    float e2 = bf2f(s_eb[j2 * ROWP + m]), e3 = bf2f(s_eb[j3 * ROWP + m]);
                    const uint4* ep0 = (const uint4*)(s_poolh + (base + kn) * FEc);
                    uint4 a0 = ep0[0], a1 = ep0[1], b0 = ep0[2], b1 = ep0[3];
                    uint4 c0 = ep0[4], c1 = ep0[5], d0 = ep0[6], d1 = ep0[7];
                    float q0, q1, q2, q3;
                    EP_DOT(a0, a1, q0); EP_DOT(b0, b1, q1);
                    EP_DOT(c0, c1, q2); EP_DOT(d0, d1, q3);
                    float w0 = __expf(fast_tanh(q0 + n0));
                    float w1 = __expf(fast_tanh(q1 + n1));
                    float w2 = __expf(fast_tanh(q2 + n2));
                    float w3 = __expf(fast_tanh(q3 + n3));
                    pden += w0 + w1 + w2 + w3;
                    pnum += w0 * e0 + w1 * e1 + w2 * e2 + w3 * e3;
                }
                // ---- remainder (<4) ----
#pragma unroll 1
                for (; kn < cap; ++kn) {
                    int j = s_nbr[i][kn];
                    const uint4* e = (const uint4*)(s_poolh + (base + kn) * FEc);
                    uint4 p0 = e[0], p1 = e[1];
                    float ep;
                    EP_DOT(p0, p1, ep);
                    float x = ep + s_np[j * NPP + m];
                    float w = __expf(fast_tanh(x));   // logits in (-1,1): no max-sub needed
                    pden += w;
                    pnum += w * bf2f(s_eb[j * ROWP + m]);
                }
                // ---- pool-overflow tail (statistically never) ----
#pragma unroll 1
                for (; kn < cnt; ++kn) {
                    int j = s_nbr[i][kn];
                    const float4* ef = (const float4*)(edges_b + ((size_t)i * Nc + j) * FEc);
                    float4 a0 = ef[0], a1 = ef[1], a2 = ef[2], a3 = ef[3];
                    float ep = a0.x*We[0*Mc+m] + a0.y*We[1*Mc+m] + a0.z*We[2*Mc+m] + a0.w*We[3*Mc+m]
                             + a1.x*We[4*Mc+m] + a1.y*We[5*Mc+m] + a1.z*We[6*Mc+m] + a1.w*We[7*Mc+m]
                             + a2.x*We[8*Mc+m] + a2.y*We[9*Mc+m] + a2.z*We[10*Mc+m]+ a2.w*We[11*Mc+m]
                             + a3.x*We[12*Mc+m]+ a3.y*We[13*Mc+m]+ a3.z*We[14*Mc+m]+ a3.w*We[15*Mc+m];
                    float w = __expf(fast_tanh(ep + s_np[j * NPP + m]));
                    pden += w;
                    pnum += w * bf2f(s_eb[j * ROWP + m]);
                }
                s_mb[i * ROWP + m] = f2bf((cnt > 0) ? pnum * fast_rcp(pden) : 0.f);
            }
#undef EP_DOT
        }
        __syncthreads();

        // ---- GRU alpha: r (fp32 in s_np), z (bf16 in s_eb); 1 acc set live ----
#pragma unroll 1
        for (int grp = 0; grp < 2; ++grp) {
            float bb = bi[grp * 128 + col] + bh[grp * 128 + col];
#pragma unroll 1
            for (int mt = 0; mt < 3; ++mt) {
                floatx4 acc = {0.f,0.f,0.f,0.f};
#pragma unroll 1
                for (int kt = 0; kt < 4; ++kt) {
                    acc = mm(afrag(s_mb, mt, kt, lane), bfrag(wWi, grp * 8 + wave, 4, kt, lane), acc);
                    acc = mm(afrag(s_hb, mt, kt, lane), bfrag(wWh, grp * 8 + wave, 4, kt, lane), acc);
                }
#pragma unroll
                for (int reg = 0; reg < 4; ++reg) {
                    int row = mt * 16 + quad * 4 + reg;
                    if (row < Nc) {
                        float sg = fast_sigmoid(acc[reg] + bb);
                        if (grp) s_eb[row * ROWP + col] = f2bf(sg);
                        else     s_np[row * NPP + col] = sg;
                    }
                }
            }
        }
        // ---- GRU beta: candidate + h update into hreg (regs private -> pre-barrier ok) ----
        {
            float bnI = bi[256 + col], bnH = bh[256 + col];
#pragma unroll
            for (int mt = 0; mt < 3; ++mt) {
                floatx4 ai = {0.f,0.f,0.f,0.f}, ah = {0.f,0.f,0.f,0.f};
#pragma unroll 1
                for (int kt = 0; kt < 4; ++kt) {
                    ai = mm(afrag(s_mb, mt, kt, lane), bfrag(wWi, 16 + wave, 4, kt, lane), ai);
                    ah = mm(afrag(s_hb, mt, kt, lane), bfrag(wWh, 16 + wave, 4, kt, lane), ah);
                }
#pragma unroll
                for (int reg = 0; reg < 4; ++reg) {
                    int row = mt * 16 + quad * 4 + reg;
                    if (row < Nc) {
                        float hold = hreg[mt][reg];
                        float r = s_np[row * NPP + col];
                        float z = bf2f(s_eb[row * ROWP + col]);
                        float n = fast_tanh(ai[reg] + bnI + r * (ah[reg] + bnH));
                        float v = (1.f - z) * n + z * hold;
                        hreg[mt][reg] = (s_cnt[row] > 0) ? v : hold;
                    }
                }
            }
        }
        __syncthreads();   // all afrag reads of s_hb complete before overwrite
#pragma unroll
        for (int mt = 0; mt < 3; ++mt)
#pragma unroll
            for (int reg = 0; reg < 4; ++reg) {
                int row = mt * 16 + quad * 4 + reg;
                if (row < Nc) s_hb[row * ROWP + col] = f2bf(hreg[mt][reg]);
            }
        __syncthreads();
    }

    // ---- Readout: out = sum_i mask * sigmoid(cat@Wg+bg) * (cat@Wo+bo) ----
    for (int idx = tid; idx < Nc * Hc; idx += T) {
        int row = idx >> 7, c2 = idx & 127;
        s_mb[row * ROWP + c2] = f2bf(nodes_b[idx]);   // cat tail (messages dead)
    }
    __syncthreads();
    float psum = 0.f;
    {
        float bgv = bg[col], bov = bo[col];
#pragma unroll 1
        for (int mt = 0; mt < 3; ++mt) {
            floatx4 ga = {0.f,0.f,0.f,0.f}, oa = {0.f,0.f,0.f,0.f};
#pragma unroll 1
            for (int kt = 0; kt < 8; ++kt) {
                short8 a = (kt < 4) ? afrag(s_hb, mt, kt, lane) : afrag(s_mb, mt, kt - 4, lane);
                ga = mm(a, bfrag(wWg, wave, 8, kt, lane), ga);
                oa = mm(a, bfrag(wWo, wave, 8, kt, lane), oa);
            }
#pragma unroll
            for (int reg = 0; reg < 4; ++reg) {
                int row = mt * 16 + quad * 4 + reg;
                if (row < Nc && s_cnt[row] > 0)
                    psum += fast_sigmoid(ga[reg] + bgv) * (oa[reg] + bov);
            }
        }
    }
    psum += __shfl_xor(psum, 16);   // reduce the 4 quads sharing this col
    psum += __shfl_xor(psum, 32);
    if (quad == 0) out[(size_t)b * OUTc + col] = psum;
}

extern "C" void kernel_launch(void* const* d_in, const int* in_sizes, int n_in,
                              void* d_out, int out_size, void* d_ws, size_t ws_size,
                              hipStream_t stream) {
    const float* nodes = (const float*)d_in[0];
    const float* edges = (const float*)d_in[1];
    const float* We = (const float*)d_in[2];
    const float* Wn = (const float*)d_in[3];
    const float* Wm = (const float*)d_in[4];
    const float* Wi = (const float*)d_in[5];
    const float* Wh = (const float*)d_in[6];
    const float* bi = (const float*)d_in[7];
    const float* bh = (const float*)d_in[8];
    const float* Wg = (const float*)d_in[9];
    const float* bg = (const float*)d_in[10];
    const float* Wo = (const float*)d_in[11];
    const float* bo = (const float*)d_in[12];
    float* out = (float*)d_out;
    unsigned short* ws = (unsigned short*)d_ws;

    prep_kernel<<<384, 64, 0, stream>>>(Wn, Wm, Wi, Wh, Wg, Wo, ws);
    mpnn_kernel<<<Bc, T, 0, stream>>>(nodes, edges, We, bi, bh, bg, bo, ws, out);
}

// Round 8
// 246.172 us; speedup vs baseline: 1.3561x; 1.1164x over previous
//
#include <hip/hip_runtime.h>

#define T 512
constexpr int Bc = 512, Nc = 40, Hc = 128, FEc = 16, Mc = 128, OUTc = 128, NPASS = 3;
constexpr int ROWP = 136;   // bf16 LDS row pitch
constexpr int NPP  = 132;   // fp32 np/r row pitch (2-way bank alias on reads/writes: free)
constexpr int EPOOL = 512;  // LDS edge pool slots (mean ~296; fallback covers overflow)

typedef __attribute__((ext_vector_type(8))) short short8;
typedef __attribute__((ext_vector_type(4))) float floatx4;
typedef __attribute__((ext_vector_type(4))) float fvec4;
typedef _Float16 half2v __attribute__((ext_vector_type(2)));
typedef _Float16 half8v __attribute__((ext_vector_type(8)));

// ws layout (bf16 elements): fragment-major B operands only (384 KB, L2-resident)
constexpr int WS_WN = 0, WS_WM = 16384, WS_WI = 32768, WS_WH = 81920, WS_WG = 131072, WS_WO = 163840;

__device__ __forceinline__ float fast_rcp(float x) { return __builtin_amdgcn_rcpf(x); }
__device__ __forceinline__ float fast_sigmoid(float x) { return fast_rcp(1.f + __expf(-x)); }
__device__ __forceinline__ float fast_tanh(float x) {
    float t = __expf(2.f * x);
    return 1.f - 2.f * fast_rcp(t + 1.f);
}
__device__ __forceinline__ float bf2f(unsigned short u) {
    union { unsigned int i; float f; } v; v.i = ((unsigned int)u) << 16; return v.f;
}
__device__ __forceinline__ unsigned short f2bf(float f) {
    union { float f; unsigned int i; } v; v.f = f;
    unsigned int r = v.i + 0x7fff + ((v.i >> 16) & 1);   // RNE
    return (unsigned short)(r >> 16);
}
__device__ __forceinline__ half2v u2h(unsigned int u) {
    union { unsigned int i; half2v h; } v; v.i = u; return v.h;
}

__device__ __forceinline__ floatx4 mm(short8 a, short8 b, floatx4 c) {
    return __builtin_amdgcn_mfma_f32_16x16x32_bf16(a, b, c, 0, 0, 0);
}
// A-fragment: A[m=lane&15][k=quad*8+j]; rows>=40 clamped (their C rows discarded)
__device__ __forceinline__ short8 afrag(const unsigned short* buf, int mt, int kt, int lane) {
    int row = mt * 16 + (lane & 15); row = row > 39 ? 39 : row;
    return *(const short8*)(buf + row * ROWP + kt * 32 + (lane >> 4) * 8);
}
__device__ __forceinline__ short8 bfrag(const unsigned short* w, int nt, int nKT, int kt, int lane) {
    return *(const short8*)(w + ((nt * nKT + kt) * 64 + lane) * 8);
}

// ---- prep: weights -> bf16 B-fragment layout in ws ----
__global__ void prep_kernel(const float* __restrict__ Wn, const float* __restrict__ Wm,
                            const float* __restrict__ Wi, const float* __restrict__ Wh,
                            const float* __restrict__ Wg, const float* __restrict__ Wo,
                            unsigned short* __restrict__ ws) {
    int c = blockIdx.x, lane = threadIdx.x;
    int quad = lane >> 4, l16 = lane & 15;
    const float* W; int N, nKT, local; unsigned short* dst;
    if (c < 32)       { W = Wn; N = 128; nKT = 4; local = c;       dst = ws + WS_WN; }
    else if (c < 64)  { W = Wm; N = 128; nKT = 4; local = c - 32;  dst = ws + WS_WM; }
    else if (c < 160) { W = Wi; N = 384; nKT = 4; local = c - 64;  dst = ws + WS_WI; }
    else if (c < 256) { W = Wh; N = 384; nKT = 4; local = c - 160; dst = ws + WS_WH; }
    else if (c < 320) { W = Wg; N = 128; nKT = 8; local = c - 256; dst = ws + WS_WG; }
    else              { W = Wo; N = 128; nKT = 8; local = c - 320; dst = ws + WS_WO; }
    int nt = local / nKT, kt = local % nKT;
    short8 v;
#pragma unroll
    for (int j = 0; j < 8; ++j) {
        int k = kt * 32 + quad * 8 + j;
        v[j] = (short)f2bf(W[k * N + nt * 16 + l16]);
    }
    *(short8*)(dst + local * 512 + lane * 8) = v;
}

// T=512, 8 waves, LDS ~70 KB -> 2 blocks/CU (4 waves/SIMD). Occupancy GRID-capped
// (512 blocks / 256 CUs = 2/CU).
// R9/R10/R12-proven anti-spill rules: (1) attention reads LDS pool only; (2) GEMM mt/kt
// loops `unroll 1`; (3) private arrays only in fully-unrolled code; (4) no per-thread
// state persists across barriers. Pool in f16 + v_dot2_f32_f16 (8 inst for the
// 16-term ep dot), np & r-gate fp32 in LDS (no pack/unpack; they never feed MFMA).
// R25 = byte-exact R17/R12: TERMINAL verified-best state (156.5 us kernel / 246.3 bench).
// Exhausted variant space (all neutral-or-regressed, do not retry):
//   R13-R16: pair-interleave, jo-table, hoist, unroll-2, LPT, h-dbuf.
//   R18: GRU B-frag hoist -> scratch spill (WRITE 16->127 MB).
//   R19: wave-ballot setup -> neutral-to--1% (setup never on critical path).
//   R20/R21: T=1024 wave-split -> spills + scheduler loss; launch_bounds 2nd arg acts
//     as min WORKGROUPS/CU here ((512,4)->64 VGPR, (1024,8)->32, (1024,2)/(512,2)->cap up
//     but occupancy/scheduling degrades). Keep (512,4).
//   R22/R23: global f16 ep cache -> attention is NOT VALU-bound; swapped ~25cy fdot2
//     for ~200-900cy dependent loads (VALU 48->36 but dur 158->191).
//   R24: 4-edge batched LDS loads + (512,2) -> dur 183, occupancy 37->22.
// Diagnosis: latency/structure plateau. HBM 5%, MfmaUtil 6% (= ~150 TF effective on the
// ~20 GFLOP of tiny GEMMs actually present), VALU 48%, 2 blocks/CU. Not a HW roofline;
// the 64-VGPR regalloc point + barrier-phased structure defends this local minimum.
__global__ __launch_bounds__(T, 4) void mpnn_kernel(
    const float* __restrict__ nodes, const float* __restrict__ edges,
    const float* __restrict__ We, const float* __restrict__ bi,
    const float* __restrict__ bh, const float* __restrict__ bg,
    const float* __restrict__ bo, const unsigned short* __restrict__ ws,
    float* __restrict__ out)
{
    __shared__ __attribute__((aligned(16))) unsigned short s_hb[Nc * ROWP];   // bf16 h
    __shared__ __attribute__((aligned(16))) unsigned short s_mb[Nc * ROWP];   // messages / nodes(cat)
    __shared__ __attribute__((aligned(16))) float s_np[Nc * NPP];             // np fp32, then r-gate fp32
    __shared__ __attribute__((aligned(16))) unsigned short s_eb[Nc * ROWP];   // emb, then z (init: slot_src)
    __shared__ __attribute__((aligned(16))) _Float16 s_poolh[EPOOL * FEc];    // 16 KB f16 edge features
    __shared__ unsigned char s_nbr[Nc][Nc];
    __shared__ int s_cnt[Nc];
    __shared__ int s_off[Nc];
    __shared__ int s_total;

    const int b = blockIdx.x, tid = threadIdx.x;
    const int lane = tid & 63, wave = tid >> 6;          // 8 waves; nt = wave
    const int quad = lane >> 4, l16 = lane & 15;
    const int m = tid & 127, g = tid >> 7;               // attention: g in 0..3
    const int col = wave * 16 + l16;

    const float* nodes_b = nodes + (size_t)b * Nc * Hc;
    const float* edges_b = edges + (size_t)b * Nc * Nc * FEc;
    const unsigned short* wWn = ws + WS_WN; const unsigned short* wWm = ws + WS_WM;
    const unsigned short* wWi = ws + WS_WI; const unsigned short* wWh = ws + WS_WH;
    const unsigned short* wWg = ws + WS_WG; const unsigned short* wWo = ws + WS_WO;

    // ---- init: h fp32 in registers (static map, fully unrolled), bf16 in LDS ----
    float hreg[3][4];
#pragma unroll
    for (int mt = 0; mt < 3; ++mt)
#pragma unroll
        for (int reg = 0; reg < 4; ++reg) {
            int row = mt * 16 + quad * 4 + reg;
            float v = (row < Nc) ? nodes_b[row * Hc + col] : 0.f;
            hreg[mt][reg] = v;
            if (row < Nc) s_hb[row * ROWP + col] = f2bf(v);
        }
    // ---- adjacency scan (streaming, non-temporal) ----
    for (int p = tid; p < Nc * Nc; p += T) {
        const fvec4* e4 = (const fvec4*)(edges_b + p * FEc);
        fvec4 a0 = __builtin_nontemporal_load(e4);
        fvec4 a1 = __builtin_nontemporal_load(e4 + 1);
        fvec4 a2 = __builtin_nontemporal_load(e4 + 2);
        fvec4 a3 = __builtin_nontemporal_load(e4 + 3);
        float s = a0.x + a0.y + a0.z + a0.w + a1.x + a1.y + a1.z + a1.w
                + a2.x + a2.y + a2.z + a2.w + a3.x + a3.y + a3.z + a3.w;
        ((unsigned char*)s_nbr)[p] = (s > 0.f) ? 1 : 0;
    }
    __syncthreads();
    if (tid < Nc) {               // compact neighbor list in place
        int c = 0;
#pragma unroll 1
        for (int j = 0; j < Nc; ++j)
            if (s_nbr[tid][j]) { s_nbr[tid][c] = (unsigned char)j; ++c; }
        s_cnt[tid] = c;
    }
    __syncthreads();
    if (tid == 0) {
        int tot = 0;
#pragma unroll 1
        for (int i = 0; i < Nc; ++i) { s_off[i] = tot; tot += s_cnt[i]; }
        s_total = tot;
    }
    __syncthreads();
    int* slot_src = (int*)s_eb;   // temp alias; dead before pass-0 Phase A writes s_eb
    if (tid < Nc) {
        int base = s_off[tid], cnt = s_cnt[tid];
#pragma unroll 1
        for (int kn = 0; kn < cnt; ++kn) {
            int slot = base + kn;
            if (slot < EPOOL) slot_src[slot] = tid * Nc + s_nbr[tid][kn];
        }
    }
    __syncthreads();
    {   // fill compact f16 edge pool (once; reused all 3 passes)
        const int E = s_total < EPOOL ? s_total : EPOOL;
#pragma unroll 1
        for (int w = tid; w < E * 2; w += T) {
            int s = w >> 1, hf = w & 1;
            const float* src = edges_b + (size_t)slot_src[s] * FEc + hf * 8;
            fvec4 x = __builtin_nontemporal_load((const fvec4*)src);
            fvec4 y = __builtin_nontemporal_load((const fvec4*)(src + 4));
            half8v v;
            v[0] = (_Float16)x.x; v[1] = (_Float16)x.y; v[2] = (_Float16)x.z; v[3] = (_Float16)x.w;
            v[4] = (_Float16)y.x; v[5] = (_Float16)y.y; v[6] = (_Float16)y.z; v[7] = (_Float16)y.w;
            *(half8v*)(s_poolh + s * FEc + hf * 8) = v;
        }
    }
    __syncthreads();

    for (int pass = 0; pass < NPASS; ++pass) {
        // ---- Phase A: np = h@Wn (fp32 out), emb = h@Wm (bf16 out) ----
#pragma unroll 1
        for (int jb = 0; jb < 2; ++jb) {
            const unsigned short* wb = jb ? wWm : wWn;
            short8 bfr[4];
#pragma unroll
            for (int kt = 0; kt < 4; ++kt) bfr[kt] = bfrag(wb, wave, 4, kt, lane);
#pragma unroll 1
            for (int mt = 0; mt < 3; ++mt) {
                floatx4 acc = {0.f, 0.f, 0.f, 0.f};
#pragma unroll
                for (int kt = 0; kt < 4; ++kt) acc = mm(afrag(s_hb, mt, kt, lane), bfr[kt], acc);
#pragma unroll
                for (int reg = 0; reg < 4; ++reg) {
                    int row = mt * 16 + quad * 4 + reg;
                    if (row < Nc) {
                        if (jb) s_eb[row * ROWP + col] = f2bf(acc[reg]);
                        else    s_np[row * NPP + col] = acc[reg];
                    }
                }
            }
        }
        __syncthreads();

        // ---- Attention: f16 pool + v_dot2_f32_f16 (~22 inst/edge) ----
        {
#if __has_builtin(__builtin_amdgcn_fdot2)
            half2v wh[8];
#pragma unroll
            for (int f = 0; f < 8; ++f)
                wh[f] = (half2v){(_Float16)We[(2 * f) * Mc + m], (_Float16)We[(2 * f + 1) * Mc + m]};
#else
            float wef[FEc];
#pragma unroll
            for (int f = 0; f < FEc; ++f) wef[f] = We[f * Mc + m];
#endif
#pragma unroll 1
            for (int ib = 0; ib < 10; ++ib) {
                int i = g + ib * 4;
                int cnt = s_cnt[i], base = s_off[i];
                int cap = EPOOL - base; if (cap > cnt) cap = cnt; if (cap < 0) cap = 0;
                float pden = 0.f, pnum = 0.f;
                int kn = 0;
#pragma unroll 1
                for (; kn < cap; ++kn) {
                    int j = s_nbr[i][kn];
                    const uint4* e = (const uint4*)(s_poolh + (base + kn) * FEc);
                    uint4 p0 = e[0], p1 = e[1];
#if __has_builtin(__builtin_amdgcn_fdot2)
                    float ep = 0.f;
                    ep = __builtin_amdgcn_fdot2(u2h(p0.x), wh[0], ep, false);
                    ep = __builtin_amdgcn_fdot2(u2h(p0.y), wh[1], ep, false);
                    ep = __builtin_amdgcn_fdot2(u2h(p0.z), wh[2], ep, false);
                    ep = __builtin_amdgcn_fdot2(u2h(p0.w), wh[3], ep, false);
                    ep = __builtin_amdgcn_fdot2(u2h(p1.x), wh[4], ep, false);
                    ep = __builtin_amdgcn_fdot2(u2h(p1.y), wh[5], ep, false);
                    ep = __builtin_amdgcn_fdot2(u2h(p1.z), wh[6], ep, false);
                    ep = __builtin_amdgcn_fdot2(u2h(p1.w), wh[7], ep, false);
#else
                    half2v h0 = u2h(p0.x), h1 = u2h(p0.y), h2 = u2h(p0.z), h3 = u2h(p0.w);
                    half2v h4 = u2h(p1.x), h5 = u2h(p1.y), h6 = u2h(p1.z), h7 = u2h(p1.w);
                    float ep = (float)h0.x*wef[0] + (float)h0.y*wef[1] + (float)h1.x*wef[2] + (float)h1.y*wef[3]
                             + (float)h2.x*wef[4] + (float)h2.y*wef[5] + (float)h3.x*wef[6] + (float)h3.y*wef[7]
                             + (float)h4.x*wef[8] + (float)h4.y*wef[9] + (float)h5.x*wef[10]+ (float)h5.y*wef[11]
                             + (float)h6.x*wef[12]+ (float)h6.y*wef[13]+ (float)h7.x*wef[14]+ (float)h7.y*wef[15];
#endif
                    float x = ep + s_np[j * NPP + m];
                    float w = __expf(fast_tanh(x));   // logits in (-1,1): no max-sub needed
                    pden += w;
                    pnum += w * bf2f(s_eb[j * ROWP + m]);
                }
#pragma unroll 1
                for (; kn < cnt; ++kn) {   // pool-overflow tail (statistically never)
                    int j = s_nbr[i][kn];
                    const float4* ef = (const float4*)(edges_b + ((size_t)i * Nc + j) * FEc);
                    float4 a0 = ef[0], a1 = ef[1], a2 = ef[2], a3 = ef[3];
                    float ep = a0.x*We[0*Mc+m] + a0.y*We[1*Mc+m] + a0.z*We[2*Mc+m] + a0.w*We[3*Mc+m]
                             + a1.x*We[4*Mc+m] + a1.y*We[5*Mc+m] + a1.z*We[6*Mc+m] + a1.w*We[7*Mc+m]
                             + a2.x*We[8*Mc+m] + a2.y*We[9*Mc+m] + a2.z*We[10*Mc+m]+ a2.w*We[11*Mc+m]
                             + a3.x*We[12*Mc+m]+ a3.y*We[13*Mc+m]+ a3.z*We[14*Mc+m]+ a3.w*We[15*Mc+m];
                    float w = __expf(fast_tanh(ep + s_np[j * NPP + m]));
                    pden += w;
                    pnum += w * bf2f(s_eb[j * ROWP + m]);
                }
                s_mb[i * ROWP + m] = f2bf((cnt > 0) ? pnum * fast_rcp(pden) : 0.f);
            }
        }
        __syncthreads();

        // ---- GRU alpha: r (fp32 in s_np), z (bf16 in s_eb); 1 acc set live ----
#pragma unroll 1
        for (int grp = 0; grp < 2; ++grp) {
            float bb = bi[grp * 128 + col] + bh[grp * 128 + col];
#pragma unroll 1
            for (int mt = 0; mt < 3; ++mt) {
                floatx4 acc = {0.f,0.f,0.f,0.f};
#pragma unroll 1
                for (int kt = 0; kt < 4; ++kt) {
                    acc = mm(afrag(s_mb, mt, kt, lane), bfrag(wWi, grp * 8 + wave, 4, kt, lane), acc);
                    acc = mm(afrag(s_hb, mt, kt, lane), bfrag(wWh, grp * 8 + wave, 4, kt, lane), acc);
                }
#pragma unroll
                for (int reg = 0; reg < 4; ++reg) {
                    int row = mt * 16 + quad * 4 + reg;
                    if (row < Nc) {
                        float sg = fast_sigmoid(acc[reg] + bb);
                        if (grp) s_eb[row * ROWP + col] = f2bf(sg);
                        else     s_np[row * NPP + col] = sg;
                    }
                }
            }
        }
        // ---- GRU beta: candidate + h update into hreg (regs private -> pre-barrier ok) ----
        {
            float bnI = bi[256 + col], bnH = bh[256 + col];
#pragma unroll
            for (int mt = 0; mt < 3; ++mt) {
                floatx4 ai = {0.f,0.f,0.f,0.f}, ah = {0.f,0.f,0.f,0.f};
#pragma unroll 1
                for (int kt = 0; kt < 4; ++kt) {
                    ai = mm(afrag(s_mb, mt, kt, lane), bfrag(wWi, 16 + wave, 4, kt, lane), ai);
                    ah = mm(afrag(s_hb, mt, kt, lane), bfrag(wWh, 16 + wave, 4, kt, lane), ah);
                }
#pragma unroll
                for (int reg = 0; reg < 4; ++reg) {
                    int row = mt * 16 + quad * 4 + reg;
                    if (row < Nc) {
                        float hold = hreg[mt][reg];
                        float r = s_np[row * NPP + col];
                        float z = bf2f(s_eb[row * ROWP + col]);
                        float n = fast_tanh(ai[reg] + bnI + r * (ah[reg] + bnH));
                        float v = (1.f - z) * n + z * hold;
                        hreg[mt][reg] = (s_cnt[row] > 0) ? v : hold;
                    }
                }
            }
        }
        __syncthreads();   // all afrag reads of s_hb complete before overwrite
#pragma unroll
        for (int mt = 0; mt < 3; ++mt)
#pragma unroll
            for (int reg = 0; reg < 4; ++reg) {
                int row = mt * 16 + quad * 4 + reg;
                if (row < Nc) s_hb[row * ROWP + col] = f2bf(hreg[mt][reg]);
            }
        __syncthreads();
    }

    // ---- Readout: out = sum_i mask * sigmoid(cat@Wg+bg) * (cat@Wo+bo) ----
    for (int idx = tid; idx < Nc * Hc; idx += T) {
        int row = idx >> 7, c2 = idx & 127;
        s_mb[row * ROWP + c2] = f2bf(nodes_b[idx]);   // cat tail (messages dead)
    }
    __syncthreads();
    float psum = 0.f;
    {
        float bgv = bg[col], bov = bo[col];
#pragma unroll 1
        for (int mt = 0; mt < 3; ++mt) {
            floatx4 ga = {0.f,0.f,0.f,0.f}, oa = {0.f,0.f,0.f,0.f};
#pragma unroll 1
            for (int kt = 0; kt < 8; ++kt) {
                short8 a = (kt < 4) ? afrag(s_hb, mt, kt, lane) : afrag(s_mb, mt, kt - 4, lane);
                ga = mm(a, bfrag(wWg, wave, 8, kt, lane), ga);
                oa = mm(a, bfrag(wWo, wave, 8, kt, lane), oa);
            }
#pragma unroll
            for (int reg = 0; reg < 4; ++reg) {
                int row = mt * 16 + quad * 4 + reg;
                if (row < Nc && s_cnt[row] > 0)
                    psum += fast_sigmoid(ga[reg] + bgv) * (oa[reg] + bov);
            }
        }
    }
    psum += __shfl_xor(psum, 16);   // reduce the 4 quads sharing this col
    psum += __shfl_xor(psum, 32);
    if (quad == 0) out[(size_t)b * OUTc + col] = psum;
}

extern "C" void kernel_launch(void* const* d_in, const int* in_sizes, int n_in,
                              void* d_out, int out_size, void* d_ws, size_t ws_size,
                              hipStream_t stream) {
    const float* nodes = (const float*)d_in[0];
    const float* edges = (const float*)d_in[1];
    const float* We = (const float*)d_in[2];
    const float* Wn = (const float*)d_in[3];
    const float* Wm = (const float*)d_in[4];
    const float* Wi = (const float*)d_in[5];
    const float* Wh = (const float*)d_in[6];
    const float* bi = (const float*)d_in[7];
    const float* bh = (const float*)d_in[8];
    const float* Wg = (const float*)d_in[9];
    const float* bg = (const float*)d_in[10];
    const float* Wo = (const float*)d_in[11];
    const float* bo = (const float*)d_in[12];
    float* out = (float*)d_out;
    unsigned short* ws = (unsigned short*)d_ws;

    prep_kernel<<<384, 64, 0, stream>>>(Wn, Wm, Wi, Wh, Wg, Wo, ws);
    mpnn_kernel<<<Bc, T, 0, stream>>>(nodes, edges, We, bi, bh, bg, bo, ws, out);
}